// Round 1
// baseline (849.561 us; speedup 1.0000x reference)
//
#include <hip/hip_runtime.h>
#include <hip/hip_bf16.h>

typedef __bf16 bf16x8 __attribute__((ext_vector_type(8)));
typedef float  f32x4  __attribute__((ext_vector_type(4)));

typedef __attribute__((address_space(1))) const void* as1_cvoidp;
typedef __attribute__((address_space(3))) void*       as3_voidp;

__device__ __forceinline__ void gload_lds16(const void* g, void* l) {
    __builtin_amdgcn_global_load_lds((as1_cvoidp)g, (as3_voidp)l, 16, 0, 0);
}

// ---------------------------------------------------------------------------
// fp32 -> bf16 convert, 8 elements/thread, grid-stride
// ---------------------------------------------------------------------------
__global__ __launch_bounds__(256)
void cvt_f32_bf16(const float* __restrict__ in, __bf16* __restrict__ out, long n8)
{
    long i = (long)blockIdx.x * blockDim.x + threadIdx.x;
    const long stride = (long)gridDim.x * blockDim.x;
    for (; i < n8; i += stride) {
        f32x4 a = ((const f32x4*)in)[2*i];
        f32x4 b = ((const f32x4*)in)[2*i + 1];
        bf16x8 o;
        #pragma unroll
        for (int j = 0; j < 4; ++j) { o[j] = (__bf16)a[j]; o[4+j] = (__bf16)b[j]; }
        ((bf16x8*)out)[i] = o;
    }
}

// ---------------------------------------------------------------------------
// NT GEMM: C[M,N] = alpha * (A[M,K] . B[N,K]^T) (+ bias[N])
// A, B bf16 row-major with K contiguous. 128x128 tile, BK=32, 4 waves (2x2),
// each wave 64x64 = 4x4 fragments of 16x16x32 MFMA. global_load_lds staging.
// Grid: (M/128, N/128, batch)
// ---------------------------------------------------------------------------
template<bool BIAS, bool OUTBF16>
__global__ __launch_bounds__(256)
void gemm_nt(const __bf16* __restrict__ A, const __bf16* __restrict__ B,
             void* __restrict__ Cout, const float* __restrict__ bias,
             int N, int K, float alpha, long sA, long sB, long sC)
{
    __shared__ __bf16 As[128 * 32];
    __shared__ __bf16 Bs[128 * 32];

    const int tid  = threadIdx.x;
    const int wave = tid >> 6;
    const int lane = tid & 63;
    const long bz  = blockIdx.z;

    const __bf16* pA = A + bz * sA;
    const __bf16* pB = B + bz * sB;

    const int wm = wave >> 1, wn = wave & 1;

    f32x4 acc[4][4] = {};

    // staging: thread tid loads 16B; row = tid/4, kcol = (tid%4)*8 ; two row-halves
    const int srow = tid >> 2;
    const int scol = (tid & 3) << 3;
    const __bf16* gA0 = pA + (long)(blockIdx.x * 128 + srow) * K + scol;
    const __bf16* gB0 = pB + (long)(blockIdx.y * 128 + srow) * K + scol;
    const long rstep = 64L * K;
    char* lA = (char*)As + wave * 1024;   // wave-uniform LDS base (+ lane*16 by HW)
    char* lB = (char*)Bs + wave * 1024;

    // fragment read offsets (elements): row*32 + kgroup*8
    const int aro = (wm * 64 + (lane & 15)) * 32 + ((lane >> 4) << 3);
    const int bro = (wn * 64 + (lane & 15)) * 32 + ((lane >> 4) << 3);

    for (int kt = 0; kt < K; kt += 32) {
        gload_lds16(gA0 + kt,         lA);
        gload_lds16(gA0 + rstep + kt, lA + 4096);
        gload_lds16(gB0 + kt,         lB);
        gload_lds16(gB0 + rstep + kt, lB + 4096);
        __syncthreads();

        bf16x8 af[4], bfr[4];
        #pragma unroll
        for (int i = 0; i < 4; ++i) af[i]  = *(const bf16x8*)(As + aro + i * 16 * 32);
        #pragma unroll
        for (int i = 0; i < 4; ++i) bfr[i] = *(const bf16x8*)(Bs + bro + i * 16 * 32);

        #pragma unroll
        for (int mi = 0; mi < 4; ++mi)
            #pragma unroll
            for (int ni = 0; ni < 4; ++ni)
                acc[mi][ni] = __builtin_amdgcn_mfma_f32_16x16x32_bf16(
                    af[mi], bfr[ni], acc[mi][ni], 0, 0, 0);
        __syncthreads();
    }

    // C/D layout: col = lane&15, row = (lane>>4)*4 + j   [m89/m91-verified]
    const int row0 = blockIdx.x * 128 + wm * 64 + ((lane >> 4) << 2);
    const int col0 = blockIdx.y * 128 + wn * 64 + (lane & 15);

    float bvv[4];
    if (BIAS) {
        #pragma unroll
        for (int ni = 0; ni < 4; ++ni) bvv[ni] = bias[col0 + ni * 16];
    }

    if (OUTBF16) {
        __bf16* C = (__bf16*)Cout + bz * sC;
        #pragma unroll
        for (int mi = 0; mi < 4; ++mi)
            #pragma unroll
            for (int ni = 0; ni < 4; ++ni)
                #pragma unroll
                for (int j = 0; j < 4; ++j) {
                    float v = acc[mi][ni][j] * alpha;
                    if (BIAS) v += bvv[ni];
                    C[(long)(row0 + mi * 16 + j) * N + col0 + ni * 16] = (__bf16)v;
                }
    } else {
        float* C = (float*)Cout + bz * sC;
        #pragma unroll
        for (int mi = 0; mi < 4; ++mi)
            #pragma unroll
            for (int ni = 0; ni < 4; ++ni)
                #pragma unroll
                for (int j = 0; j < 4; ++j) {
                    float v = acc[mi][ni][j] * alpha;
                    if (BIAS) v += bvv[ni];
                    C[(long)(row0 + mi * 16 + j) * N + col0 + ni * 16] = v;
                }
    }
}

// ---------------------------------------------------------------------------
// bf16 transpose: in [T][D] -> out [D][T], 64x64 tiles via LDS
// Grid: (T/64, D/64, batch)
// ---------------------------------------------------------------------------
__global__ __launch_bounds__(256)
void transpose64(const __bf16* __restrict__ in, __bf16* __restrict__ out,
                 int T, int D, long sIn, long sOut)
{
    __shared__ __bf16 tile[64][72];   // 72*2=144B row stride keeps 16B alignment
    const __bf16* pin  = in  + (long)blockIdx.z * sIn;
    __bf16*       pout = out + (long)blockIdx.z * sOut;
    const int t0 = blockIdx.x * 64, d0 = blockIdx.y * 64;
    const int tid = threadIdx.x;
    const int rr = tid >> 3;          // 0..31
    const int cc = (tid & 7) * 8;     // 0..56

    #pragma unroll
    for (int it = 0; it < 2; ++it) {
        int r = rr + it * 32;
        bf16x8 v = *(const bf16x8*)(pin + (long)(t0 + r) * D + d0 + cc);
        *(bf16x8*)&tile[r][cc] = v;
    }
    __syncthreads();
    #pragma unroll
    for (int it = 0; it < 2; ++it) {
        int dr = rr + it * 32;        // local d
        bf16x8 o;
        #pragma unroll
        for (int j = 0; j < 8; ++j) o[j] = tile[cc + j][dr];
        *(bf16x8*)(pout + (long)(d0 + dr) * T + t0 + cc) = o;
    }
}

// ---------------------------------------------------------------------------
// in-place row softmax over 4096 bf16 columns, one block (256 thr) per row
// ---------------------------------------------------------------------------
__global__ __launch_bounds__(256)
void softmax4096(__bf16* __restrict__ S)
{
    __shared__ float red[4];
    __bf16* p = S + (long)blockIdx.x * 4096;
    const int tid = threadIdx.x, lane = tid & 63, wave = tid >> 6;

    bf16x8 v0 = ((const bf16x8*)p)[tid];
    bf16x8 v1 = ((const bf16x8*)p)[tid + 256];
    float x[16];
    #pragma unroll
    for (int j = 0; j < 8; ++j) { x[j] = (float)v0[j]; x[8+j] = (float)v1[j]; }

    float m = x[0];
    #pragma unroll
    for (int j = 1; j < 16; ++j) m = fmaxf(m, x[j]);
    #pragma unroll
    for (int off = 32; off; off >>= 1) m = fmaxf(m, __shfl_xor(m, off));
    if (lane == 0) red[wave] = m;
    __syncthreads();
    m = fmaxf(fmaxf(red[0], red[1]), fmaxf(red[2], red[3]));

    float s = 0.f;
    #pragma unroll
    for (int j = 0; j < 16; ++j) { x[j] = __expf(x[j] - m); s += x[j]; }
    #pragma unroll
    for (int off = 32; off; off >>= 1) s += __shfl_xor(s, off);
    __syncthreads();
    if (lane == 0) red[wave] = s;
    __syncthreads();
    s = red[0] + red[1] + red[2] + red[3];

    const float inv = 1.f / s;
    bf16x8 o0, o1;
    #pragma unroll
    for (int j = 0; j < 8; ++j) { o0[j] = (__bf16)(x[j]*inv); o1[j] = (__bf16)(x[8+j]*inv); }
    ((bf16x8*)p)[tid]       = o0;
    ((bf16x8*)p)[tid + 256] = o1;
}

// ---------------------------------------------------------------------------
extern "C" void kernel_launch(void* const* d_in, const int* in_sizes, int n_in,
                              void* d_out, int out_size, void* d_ws, size_t ws_size,
                              hipStream_t stream)
{
    const float* x  = (const float*)d_in[0];
    const float* Wq = (const float*)d_in[1];
    const float* bq = (const float*)d_in[2];
    const float* Wk = (const float*)d_in[3];
    const float* bk = (const float*)d_in[4];
    const float* Wv = (const float*)d_in[5];
    const float* bv = (const float*)d_in[6];
    float* out = (float*)d_out;

    const long Bn = 4, T = 4096, E = 1024, D = 1024;
    const long TD = T * D;               // 4,194,304 elts
    const long TT = T * T;               // 16,777,216 elts
    const size_t wbytes = (size_t)D * E * 2;   // 2 MB
    const size_t tdb    = (size_t)TD * 2;      // 8 MB (one batch of q/k/v)
    const float ALPHA_S = 1.0f / 32.0f;        // 1/sqrt(1024)

    const size_t need_full = 3*wbytes + 5*(size_t)Bn*tdb + (size_t)Bn*TT*2; // ~308 MB
    const size_t need_B    = 3*wbytes + 5*(size_t)Bn*tdb + (size_t)TT*2;    // ~208 MB

    char* p = (char*)d_ws;
    auto bump = [&](size_t bytes) { char* r = p; p += bytes; return r; };

    __bf16* wqb = (__bf16*)bump(wbytes);
    __bf16* wkb = (__bf16*)bump(wbytes);
    __bf16* wvb = (__bf16*)bump(wbytes);

    // convert weights (once for all tiers)
    cvt_f32_bf16<<<512, 256, 0, stream>>>(Wq, wqb, D*E/8);
    cvt_f32_bf16<<<512, 256, 0, stream>>>(Wk, wkb, D*E/8);
    cvt_f32_bf16<<<512, 256, 0, stream>>>(Wv, wvb, D*E/8);

    if (ws_size >= need_B) {
        const bool fullS = (ws_size >= need_full);
        __bf16* xb   = (__bf16*)bump(Bn * tdb);
        __bf16* q    = (__bf16*)bump(Bn * tdb);
        __bf16* k    = (__bf16*)bump(Bn * tdb);
        __bf16* vtmp = (__bf16*)bump(Bn * tdb);
        __bf16* vt   = (__bf16*)bump(Bn * tdb);
        __bf16* S    = (__bf16*)bump(fullS ? (size_t)Bn*TT*2 : (size_t)TT*2);

        cvt_f32_bf16<<<4096, 256, 0, stream>>>(x, xb, Bn*T*E/8);

        dim3 gp(128, 8, 1);   // M=16384, N=1024
        gemm_nt<true,true><<<gp, 256, 0, stream>>>(xb, wqb, q,    bq, 1024, 1024, 1.f, 0,0,0);
        gemm_nt<true,true><<<gp, 256, 0, stream>>>(xb, wkb, k,    bk, 1024, 1024, 1.f, 0,0,0);
        gemm_nt<true,true><<<gp, 256, 0, stream>>>(xb, wvb, vtmp, bv, 1024, 1024, 1.f, 0,0,0);

        transpose64<<<dim3(64,16,Bn), 256, 0, stream>>>(vtmp, vt, (int)T, (int)D, TD, TD);

        if (fullS) {
            gemm_nt<false,true><<<dim3(32,32,Bn), 256, 0, stream>>>(
                q, k, S, nullptr, 4096, 1024, ALPHA_S, TD, TD, TT);
            softmax4096<<<Bn*T, 256, 0, stream>>>(S);
            gemm_nt<false,false><<<dim3(32,8,Bn), 256, 0, stream>>>(
                S, vt, out, nullptr, 1024, 4096, 1.f, TT, TD, TD);
        } else {
            for (int b = 0; b < Bn; ++b) {
                gemm_nt<false,true><<<dim3(32,32,1), 256, 0, stream>>>(
                    q + b*TD, k + b*TD, S, nullptr, 4096, 1024, ALPHA_S, 0,0,0);
                softmax4096<<<T, 256, 0, stream>>>(S);
                gemm_nt<false,false><<<dim3(32,8,1), 256, 0, stream>>>(
                    S, vt + b*TD, out + b*TD, nullptr, 1024, 4096, 1.f, 0,0,0);
            }
        }
    } else {
        // tier C: fully per-batch (~82 MB)
        __bf16* xb   = (__bf16*)bump(tdb);
        __bf16* q    = (__bf16*)bump(tdb);
        __bf16* k    = (__bf16*)bump(tdb);
        __bf16* vtmp = (__bf16*)bump(tdb);
        __bf16* vt   = (__bf16*)bump(tdb);
        __bf16* S    = (__bf16*)bump((size_t)TT * 2);

        for (int b = 0; b < Bn; ++b) {
            cvt_f32_bf16<<<2048, 256, 0, stream>>>(x + b*T*E, xb, T*E/8);
            dim3 gp(32, 8, 1);  // M=4096, N=1024
            gemm_nt<true,true><<<gp, 256, 0, stream>>>(xb, wqb, q,    bq, 1024, 1024, 1.f, 0,0,0);
            gemm_nt<true,true><<<gp, 256, 0, stream>>>(xb, wkb, k,    bk, 1024, 1024, 1.f, 0,0,0);
            gemm_nt<true,true><<<gp, 256, 0, stream>>>(xb, wvb, vtmp, bv, 1024, 1024, 1.f, 0,0,0);
            transpose64<<<dim3(64,16,1), 256, 0, stream>>>(vtmp, vt, (int)T, (int)D, 0, 0);
            gemm_nt<false,true><<<dim3(32,32,1), 256, 0, stream>>>(
                q, k, S, nullptr, 4096, 1024, ALPHA_S, 0,0,0);
            softmax4096<<<T, 256, 0, stream>>>(S);
            gemm_nt<false,false><<<dim3(32,8,1), 256, 0, stream>>>(
                S, vt, out + b*TD, nullptr, 1024, 4096, 1.f, 0,0,0);
        }
    }
}

// Round 2
// 560.664 us; speedup vs baseline: 1.5153x; 1.5153x over previous
//
#include <hip/hip_runtime.h>
#include <hip/hip_bf16.h>

typedef __bf16 bf16x8 __attribute__((ext_vector_type(8)));
typedef float  f32x4  __attribute__((ext_vector_type(4)));

typedef __attribute__((address_space(1))) const void* as1p;
typedef __attribute__((address_space(3))) void*       as3p;

__device__ __forceinline__ void gl16(const void* g, void* l) {
    __builtin_amdgcn_global_load_lds((as1p)g, (as3p)l, 16, 0, 0);
}
#define MEMFENCE asm volatile("" ::: "memory")

// ---------------------------------------------------------------------------
// fp32 -> bf16 convert, 8 elements/thread, grid-stride
// ---------------------------------------------------------------------------
__global__ __launch_bounds__(256)
void cvt_f32_bf16(const float* __restrict__ in, __bf16* __restrict__ out, long n8)
{
    long i = (long)blockIdx.x * blockDim.x + threadIdx.x;
    const long stride = (long)gridDim.x * blockDim.x;
    for (; i < n8; i += stride) {
        f32x4 a = ((const f32x4*)in)[2*i];
        f32x4 b = ((const f32x4*)in)[2*i + 1];
        bf16x8 o;
        #pragma unroll
        for (int j = 0; j < 4; ++j) { o[j] = (__bf16)a[j]; o[4+j] = (__bf16)b[j]; }
        ((bf16x8*)out)[i] = o;
    }
}

__global__ __launch_bounds__(256)
void pack_bias(const float* __restrict__ a, const float* __restrict__ b,
               const float* __restrict__ c, float* __restrict__ o)
{
    int i = blockIdx.x * 256 + threadIdx.x;   // 3072 total
    const float* s = (i < 1024) ? a : (i < 2048) ? b : c;
    o[i] = s[i & 1023];
}

// ---------------------------------------------------------------------------
// 256x256-tile NT GEMM, BK=32, 8 waves (2Mx4N), 4-deep LDS ring, counted vmcnt.
// C[M,N] = A[M,K] . B[N,K]^T (bf16 in, f32 acc).
// EPI 0: +bias[col], bf16 out (z = weight index)
// EPI 1: exp(acc*alpha), bf16 out + per-(z,colblock) row sums (z = batch)
// EPI 2: f32 out, divide by rowsum aux (z = batch)
// EPI 3: f32 partial out, split-K (z = kz; last kz -> C1)
// ---------------------------------------------------------------------------
template<int EPI>
__global__ __launch_bounds__(512, 2)
void gemm8p(const __bf16* __restrict__ A, const __bf16* __restrict__ B,
            void* __restrict__ C0, void* __restrict__ C1,
            const float* __restrict__ aux, float* __restrict__ psum,
            int ldA, int ldB, int ldC, int Ktiles,
            long szA, long szB, long szC, long szAux, long szPsum,
            int nkz, float alpha)
{
    __shared__ char lds[131072];   // 4 bufs x (A 16K + B 16K)

    const int tid  = threadIdx.x;
    const int wave = tid >> 6, lane = tid & 63;
    const int wm = wave >> 2, wn = wave & 3;          // 2 x 4 wave grid
    const int rl = lane & 15, kg = lane >> 4;
    const int z  = blockIdx.z;

    const __bf16* Ab = A + (long)z * ((EPI == 0) ? 0 : szA);
    const __bf16* Bb = B + (long)z * szB;

    // ---- staging addresses (thread -> 16B granule, inverse-swizzled source)
    const int srow = tid >> 2;                         // 0..127 within half
    const int scol = ((tid & 3) * 8) ^ ((srow & 3) << 3);  // element offset
    const __bf16* gA0 = Ab + (long)(blockIdx.x * 256 + srow) * ldA + scol;
    const __bf16* gA1 = gA0 + (long)128 * ldA;
    const __bf16* gB0 = Bb + (long)(blockIdx.y * 256 + srow) * ldB + scol;
    const __bf16* gB1 = gB0 + (long)128 * ldB;
    char* lw = lds + wave * 1024;                      // wave-uniform LDS chunk

    // ---- fragment read offsets (swizzled)
    const int swz  = (kg * 16) ^ ((rl & 3) << 4);
    const int aoff = wm * 8192 + rl * 64 + swz;
    const int boff = 16384 + (wn >> 1) * 8192 + ((wn & 1) * 64 + rl) * 64 + swz;

    // ---- prologue: stage tiles 0..2, wait tile 0
    #pragma unroll
    for (int tt = 0; tt < 3; ++tt) {
        char* d = lw + tt * 32768;
        const long co = (long)tt * 32;
        gl16(gA0 + co, d);
        gl16(gA1 + co, d + 8192);
        gl16(gB0 + co, d + 16384);
        gl16(gB1 + co, d + 24576);
    }
    asm volatile("s_waitcnt vmcnt(8)" ::: "memory");
    __builtin_amdgcn_s_barrier();
    MEMFENCE;

    f32x4 acc[8][4] = {};

    for (int t = 0; t < Ktiles; ++t) {
        const char* rb = lds + (t & 3) * 32768;
        char* sb = lw + ((t + 3) & 3) * 32768;
        const long co = (long)(t + 3) * 32;
        bf16x8 a[4], b[4];

        // ---- phase 0: read A(mi0-3), B(ni0-3); stage next A-halves
        #pragma unroll
        for (int i = 0; i < 4; ++i) a[i] = *(const bf16x8*)(rb + aoff + i * 1024);
        #pragma unroll
        for (int i = 0; i < 4; ++i) b[i] = *(const bf16x8*)(rb + boff + i * 1024);
        if (t < Ktiles - 3) { gl16(gA0 + co, sb); gl16(gA1 + co, sb + 8192); }
        MEMFENCE;
        __builtin_amdgcn_s_barrier();
        MEMFENCE;
        __builtin_amdgcn_s_setprio(1);
        #pragma unroll
        for (int mi = 0; mi < 4; ++mi)
            #pragma unroll
            for (int ni = 0; ni < 4; ++ni)
                acc[mi][ni] = __builtin_amdgcn_mfma_f32_16x16x32_bf16(
                    a[mi], b[ni], acc[mi][ni], 0, 0, 0);
        __builtin_amdgcn_s_setprio(0);
        MEMFENCE;
        __builtin_amdgcn_s_barrier();
        MEMFENCE;

        // ---- phase 1: read A(mi4-7); stage next B-halves; counted vmcnt
        #pragma unroll
        for (int i = 0; i < 4; ++i) a[i] = *(const bf16x8*)(rb + aoff + (4 + i) * 1024);
        if (t < Ktiles - 3) { gl16(gB0 + co, sb + 16384); gl16(gB1 + co, sb + 24576); }
        if (t < Ktiles - 3)       asm volatile("s_waitcnt vmcnt(8)" ::: "memory");
        else if (t == Ktiles - 3) asm volatile("s_waitcnt vmcnt(4)" ::: "memory");
        else if (t == Ktiles - 2) asm volatile("s_waitcnt vmcnt(0)" ::: "memory");
        MEMFENCE;
        __builtin_amdgcn_s_barrier();
        MEMFENCE;
        __builtin_amdgcn_s_setprio(1);
        #pragma unroll
        for (int mi = 0; mi < 4; ++mi)
            #pragma unroll
            for (int ni = 0; ni < 4; ++ni)
                acc[4 + mi][ni] = __builtin_amdgcn_mfma_f32_16x16x32_bf16(
                    a[mi], b[ni], acc[4 + mi][ni], 0, 0, 0);
        __builtin_amdgcn_s_setprio(0);
        MEMFENCE;
        __builtin_amdgcn_s_barrier();
        MEMFENCE;
    }

    // ---- epilogue (C/D layout: row = (lane>>4)*4+j, col = lane&15; verified r1)
    const int rowg = blockIdx.x * 256 + wm * 128 + kg * 4;
    const int colg = blockIdx.y * 256 + wn * 64 + rl;

    if (EPI == 0) {
        __bf16* C = (__bf16*)C0 + (long)z * szC;
        const float* bb = aux + (long)z * szAux;
        float bv[4];
        #pragma unroll
        for (int ni = 0; ni < 4; ++ni) bv[ni] = bb[colg + ni * 16];
        #pragma unroll
        for (int mi = 0; mi < 8; ++mi)
            #pragma unroll
            for (int j = 0; j < 4; ++j) {
                __bf16* cr = C + (long)(rowg + mi * 16 + j) * ldC + colg;
                #pragma unroll
                for (int ni = 0; ni < 4; ++ni)
                    cr[ni * 16] = (__bf16)(acc[mi][ni][j] + bv[ni]);
            }
    } else if (EPI == 1) {
        __bf16* C = (__bf16*)C0 + (long)z * szC;
        float* wsum = (float*)lds;            // [4][256], buffers are dead
        float rsm[8][4];
        #pragma unroll
        for (int mi = 0; mi < 8; ++mi)
            #pragma unroll
            for (int j = 0; j < 4; ++j) {
                float s = 0.f;
                __bf16* cr = C + (long)(rowg + mi * 16 + j) * ldC + colg;
                #pragma unroll
                for (int ni = 0; ni < 4; ++ni) {
                    float e = __expf(acc[mi][ni][j] * alpha);
                    cr[ni * 16] = (__bf16)e;
                    s += e;
                }
                rsm[mi][j] = s;
            }
        #pragma unroll
        for (int mi = 0; mi < 8; ++mi)
            #pragma unroll
            for (int j = 0; j < 4; ++j) {
                float s = rsm[mi][j];
                s += __shfl_xor(s, 1); s += __shfl_xor(s, 2);
                s += __shfl_xor(s, 4); s += __shfl_xor(s, 8);
                rsm[mi][j] = s;
            }
        if (rl == 0) {
            #pragma unroll
            for (int mi = 0; mi < 8; ++mi)
                #pragma unroll
                for (int j = 0; j < 4; ++j)
                    wsum[wn * 256 + wm * 128 + mi * 16 + kg * 4 + j] = rsm[mi][j];
        }
        __syncthreads();
        if (tid < 256) {
            float s = wsum[tid] + wsum[256 + tid] + wsum[512 + tid] + wsum[768 + tid];
            psum[(long)z * szPsum + (long)blockIdx.y * 4096 + blockIdx.x * 256 + tid] = s;
        }
    } else if (EPI == 2) {
        float* C = (float*)C0 + (long)z * szC;
        const float* rs = aux + (long)z * szAux;
        #pragma unroll
        for (int mi = 0; mi < 8; ++mi)
            #pragma unroll
            for (int j = 0; j < 4; ++j) {
                int r = rowg + mi * 16 + j;
                float inv = 1.f / rs[r];
                float* cr = C + (long)r * ldC + colg;
                #pragma unroll
                for (int ni = 0; ni < 4; ++ni) cr[ni * 16] = acc[mi][ni][j] * inv;
            }
    } else {
        float* C = (z < nkz - 1) ? ((float*)C0 + (long)z * szC) : (float*)C1;
        #pragma unroll
        for (int mi = 0; mi < 8; ++mi)
            #pragma unroll
            for (int j = 0; j < 4; ++j) {
                float* cr = C + (long)(rowg + mi * 16 + j) * ldC + colg;
                #pragma unroll
                for (int ni = 0; ni < 4; ++ni) cr[ni * 16] = acc[mi][ni][j];
            }
    }
}

// ---------------------------------------------------------------------------
// bf16 transpose: in [T][D] -> out [D][T], 64x64 tiles via LDS
// ---------------------------------------------------------------------------
__global__ __launch_bounds__(256)
void transpose64(const __bf16* __restrict__ in, __bf16* __restrict__ out,
                 int T, int D, long sIn, long sOut)
{
    __shared__ __bf16 tile[64][72];
    const __bf16* pin  = in  + (long)blockIdx.z * sIn;
    __bf16*       pout = out + (long)blockIdx.z * sOut;
    const int t0 = blockIdx.x * 64, d0 = blockIdx.y * 64;
    const int tid = threadIdx.x;
    const int rr = tid >> 3;
    const int cc = (tid & 7) * 8;

    #pragma unroll
    for (int it = 0; it < 2; ++it) {
        int r = rr + it * 32;
        bf16x8 v = *(const bf16x8*)(pin + (long)(t0 + r) * D + d0 + cc);
        *(bf16x8*)&tile[r][cc] = v;
    }
    __syncthreads();
    #pragma unroll
    for (int it = 0; it < 2; ++it) {
        int dr = rr + it * 32;
        bf16x8 o;
        #pragma unroll
        for (int j = 0; j < 8; ++j) o[j] = tile[cc + j][dr];
        *(bf16x8*)(pout + (long)(d0 + dr) * T + t0 + cc) = o;
    }
}

// rs[b][r] = sum_{cb<16} psum[b][cb][r]
__global__ __launch_bounds__(256)
void rowsum16(const float* __restrict__ psum, float* __restrict__ rs)
{
    int i = blockIdx.x * 256 + threadIdx.x;
    int b = i >> 12, r = i & 4095;
    const float* p = psum + (long)b * 65536 + r;
    float s = 0.f;
    #pragma unroll
    for (int cb = 0; cb < 16; ++cb) s += p[cb * 4096];
    rs[i] = s;
}

// out = (out + sum parts) / rs[row]
__global__ __launch_bounds__(256)
void pv_reduce(float* __restrict__ outb, const float* __restrict__ parts,
               int np, const float* __restrict__ rs)
{
    long i = ((long)blockIdx.x * 256 + threadIdx.x) * 4;
    f32x4 v = *(f32x4*)(outb + i);
    for (int p = 0; p < np; ++p)
        v += *(const f32x4*)(parts + (long)p * 4194304 + i);
    float inv = 1.f / rs[i >> 10];
    v *= inv;
    *(f32x4*)(outb + i) = v;
}

// ---------------------------------------------------------------------------
extern "C" void kernel_launch(void* const* d_in, const int* in_sizes, int n_in,
                              void* d_out, int out_size, void* d_ws, size_t ws_size,
                              hipStream_t stream)
{
    const float* x  = (const float*)d_in[0];
    const float* Wq = (const float*)d_in[1];
    const float* bq = (const float*)d_in[2];
    const float* Wk = (const float*)d_in[3];
    const float* bk = (const float*)d_in[4];
    const float* Wv = (const float*)d_in[5];
    const float* bv = (const float*)d_in[6];
    float* out = (float*)d_out;

    const long T = 4096, E = 1024, D = 1024;
    const long TD = T * D;                 // 4,194,304
    const long TT = T * T;                 // 16,777,216
    const long WB = D * E;                 // 1,048,576
    const float ALPHA = 1.0f / 32.0f;
    char* W = (char*)d_ws;

    const size_t need_A  = 275853312;   // all-batch P
    const size_t need_B2 = 191131648;   // per-batch P, split-K PV

    if (ws_size >= need_A) {
        __bf16* wall = (__bf16*)(W);
        __bf16* xb   = (__bf16*)(W + 6291456);
        __bf16* vt   = (__bf16*)(W + 39845888);
        __bf16* q    = (__bf16*)(W + 73400320);
        __bf16* k    = (__bf16*)(W + 106954752);
        __bf16* P    = (__bf16*)(W + 140509184);   // vtmp aliases P base
        float*  psum = (float*) (W + 274726912);   // [4][16][4096]
        float*  rs   = (float*) (W + 275775488);   // [4][4096]
        float*  bp   = (float*) (W + 275841024);   // [3][1024]

        pack_bias<<<12, 256, 0, stream>>>(bq, bk, bv, bp);
        cvt_f32_bf16<<<512, 256, 0, stream>>>(Wq, wall, WB/8);
        cvt_f32_bf16<<<512, 256, 0, stream>>>(Wk, wall + WB, WB/8);
        cvt_f32_bf16<<<512, 256, 0, stream>>>(Wv, wall + 2*WB, WB/8);
        cvt_f32_bf16<<<4096, 256, 0, stream>>>(x, xb, 4*TD/8);

        // projections: M=16384, N=1024, z = {q,k,v}; v -> vtmp(=P base)
        gemm8p<0><<<dim3(64,4,3), 512, 0, stream>>>(
            xb, wall, q, nullptr, bp, nullptr,
            1024, 1024, 1024, 32, 0, WB, 4*TD, 1024, 0, 0, 0.f);

        transpose64<<<dim3(64,16,4), 256, 0, stream>>>(P, vt, (int)T, (int)D, TD, TD);

        // QK^T + exp epilogue + partial row sums, z = batch
        gemm8p<1><<<dim3(16,16,4), 512, 0, stream>>>(
            q, k, P, nullptr, nullptr, psum,
            1024, 1024, 4096, 32, TD, TD, TT, 0, 65536, 0, ALPHA);

        rowsum16<<<64, 256, 0, stream>>>(psum, rs);

        // PV with rowsum divide, z = batch
        gemm8p<2><<<dim3(16,4,4), 512, 0, stream>>>(
            P, vt, out, nullptr, rs, nullptr,
            4096, 4096, 1024, 128, TT, TD, TD, 4096, 0, 0, 0.f);
    } else if (ws_size >= need_B2) {
        __bf16* wall  = (__bf16*)(W);
        __bf16* xb    = (__bf16*)(W + 6291456);     // later: parts[0..1]
        float*  parts = (float*) (W + 6291456);     // 3 x TD f32 (contiguous)
        __bf16* vt    = (__bf16*)(W + 56623104);
        __bf16* q     = (__bf16*)(W + 90177536);
        __bf16* k     = (__bf16*)(W + 123731968);
        __bf16* P     = (__bf16*)(W + 157286400);   // vtmp aliases P
        float*  psum  = (float*) (W + 190840832);   // [16][4096]
        float*  rs    = (float*) (W + 191102976);   // [4096]
        float*  bp    = (float*) (W + 191119360);

        pack_bias<<<12, 256, 0, stream>>>(bq, bk, bv, bp);
        cvt_f32_bf16<<<512, 256, 0, stream>>>(Wq, wall, WB/8);
        cvt_f32_bf16<<<512, 256, 0, stream>>>(Wk, wall + WB, WB/8);
        cvt_f32_bf16<<<512, 256, 0, stream>>>(Wv, wall + 2*WB, WB/8);
        cvt_f32_bf16<<<4096, 256, 0, stream>>>(x, xb, 4*TD/8);

        gemm8p<0><<<dim3(64,4,3), 512, 0, stream>>>(
            xb, wall, q, nullptr, bp, nullptr,
            1024, 1024, 1024, 32, 0, WB, 4*TD, 1024, 0, 0, 0.f);

        transpose64<<<dim3(64,16,4), 256, 0, stream>>>(P, vt, (int)T, (int)D, TD, TD);

        for (int b = 0; b < 4; ++b) {
            gemm8p<1><<<dim3(16,16,1), 512, 0, stream>>>(
                q + b*TD, k + b*TD, P, nullptr, nullptr, psum,
                1024, 1024, 4096, 32, 0, 0, 0, 0, 0, 0, ALPHA);
            rowsum16<<<16, 256, 0, stream>>>(psum, rs);
            // split-K PV: z = kz (4), last partial straight into out
            gemm8p<3><<<dim3(16,4,4), 512, 0, stream>>>(
                P, vt + b*TD, parts, out + b*TD, nullptr, nullptr,
                4096, 4096, 1024, 32, 1024, 1024, TD, 0, 0, 4, 0.f);
            pv_reduce<<<4096, 256, 0, stream>>>(out + b*TD, parts, 3, rs);
        }
    } else {
        // tier C2: fully per-batch (~74 MB)
        __bf16* wall  = (__bf16*)(W);
        __bf16* xb    = (__bf16*)(W + 6291456);     // later: parts[0] spans xb+q
        float*  parts = (float*) (W + 6291456);
        __bf16* q     = (__bf16*)(W + 14680064);
        __bf16* k     = (__bf16*)(W + 23068672);
        __bf16* vt    = (__bf16*)(W + 31457280);
        __bf16* P     = (__bf16*)(W + 39845888);    // vtmp aliases P
        float*  psum  = (float*) (W + 73400320);
        float*  rs    = (float*) (W + 73662464);
        float*  bp    = (float*) (W + 73678848);

        pack_bias<<<12, 256, 0, stream>>>(bq, bk, bv, bp);
        cvt_f32_bf16<<<512, 256, 0, stream>>>(Wq, wall, WB/8);
        cvt_f32_bf16<<<512, 256, 0, stream>>>(Wk, wall + WB, WB/8);
        cvt_f32_bf16<<<512, 256, 0, stream>>>(Wv, wall + 2*WB, WB/8);

        for (int b = 0; b < 4; ++b) {
            cvt_f32_bf16<<<2048, 256, 0, stream>>>(x + b*TD, xb, TD/8);
            gemm8p<0><<<dim3(16,4,1), 512, 0, stream>>>(
                xb, wall, q, nullptr, bp, nullptr,
                1024, 1024, 1024, 32, 0, 0, 0, 0, 0, 0, 0.f);
            gemm8p<0><<<dim3(16,4,1), 512, 0, stream>>>(
                xb, wall + WB, k, nullptr, bp + 1024, nullptr,
                1024, 1024, 1024, 32, 0, 0, 0, 0, 0, 0, 0.f);
            gemm8p<0><<<dim3(16,4,1), 512, 0, stream>>>(
                xb, wall + 2*WB, P, nullptr, bp + 2048, nullptr,
                1024, 1024, 1024, 32, 0, 0, 0, 0, 0, 0, 0.f);
            transpose64<<<dim3(64,16,1), 256, 0, stream>>>(P, vt, (int)T, (int)D, 0, 0);
            gemm8p<1><<<dim3(16,16,1), 512, 0, stream>>>(
                q, k, P, nullptr, nullptr, psum,
                1024, 1024, 4096, 32, 0, 0, 0, 0, 0, 0, ALPHA);
            rowsum16<<<16, 256, 0, stream>>>(psum, rs);
            gemm8p<3><<<dim3(16,4,2), 512, 0, stream>>>(
                P, vt, parts, out + b*TD, nullptr, nullptr,
                4096, 4096, 1024, 64, 2048, 2048, TD, 0, 0, 2, 0.f);
            pv_reduce<<<4096, 256, 0, stream>>>(out + b*TD, parts, 1, rs);
        }
    }
}

// Round 3
// 553.004 us; speedup vs baseline: 1.5363x; 1.0139x over previous
//
#include <hip/hip_runtime.h>
#include <hip/hip_bf16.h>

typedef __bf16 bf16x8 __attribute__((ext_vector_type(8)));
typedef float  f32x4  __attribute__((ext_vector_type(4)));

typedef __attribute__((address_space(1))) const void* as1p;
typedef __attribute__((address_space(3))) void*       as3p;

__device__ __forceinline__ void gl16(const void* g, void* l) {
    __builtin_amdgcn_global_load_lds((as1p)g, (as3p)l, 16, 0, 0);
}
#define MEMFENCE asm volatile("" ::: "memory")
#define BARRIER  do { MEMFENCE; __builtin_amdgcn_s_barrier(); MEMFENCE; } while (0)

// ---------------------------------------------------------------------------
// fp32 -> bf16 convert, 8 elements/thread, grid-stride
// ---------------------------------------------------------------------------
__global__ __launch_bounds__(256)
void cvt_f32_bf16(const float* __restrict__ in, __bf16* __restrict__ out, long n8)
{
    long i = (long)blockIdx.x * blockDim.x + threadIdx.x;
    const long stride = (long)gridDim.x * blockDim.x;
    for (; i < n8; i += stride) {
        f32x4 a = ((const f32x4*)in)[2*i];
        f32x4 b = ((const f32x4*)in)[2*i + 1];
        bf16x8 o;
        #pragma unroll
        for (int j = 0; j < 4; ++j) { o[j] = (__bf16)a[j]; o[4+j] = (__bf16)b[j]; }
        ((bf16x8*)out)[i] = o;
    }
}

__global__ __launch_bounds__(256)
void pack_bias(const float* __restrict__ a, const float* __restrict__ b,
               const float* __restrict__ c, float* __restrict__ o)
{
    int i = blockIdx.x * 256 + threadIdx.x;   // 3072 total
    const float* s = (i < 1024) ? a : (i < 2048) ? b : c;
    o[i] = s[i & 1023];
}

// ---------------------------------------------------------------------------
// 256x256-tile NT GEMM, BK=64, 8 waves (2Mx4N).
// LDS: A ring 3 x 32KB @0, B ring 2 x 32KB @98304 (160 KB total).
// st_16x32 swizzle: phys_byte = log_byte ^ ((log_byte>>9 & 1) << 5), applied
// to the staging SOURCE (LDS dest linear) and to the ds_read address.
// 4 phases/K-tile, 16 MFMA each; counted vmcnt(4) once per tile.
// EPI 0: +bias[col], bf16 out (z = weight)   EPI 1: exp(acc*alpha) + row psums
// EPI 2: f32 out / rowsum                    EPI 3: split-K f32 partials
// ---------------------------------------------------------------------------
template<int EPI>
__global__ __launch_bounds__(512, 2)
void gemm8p(const __bf16* __restrict__ A, const __bf16* __restrict__ B,
            void* __restrict__ C0, void* __restrict__ C1,
            const float* __restrict__ aux, float* __restrict__ psum,
            int ldA, int ldB, int ldC, int Ktiles,
            long szA, long szB, long szC, long szAux, long szPsum,
            int nkz, float alpha)
{
    __shared__ char lds[163840];

    const int tid  = threadIdx.x;
    const int wave = tid >> 6, lane = tid & 63;
    const int wm = wave >> 2, wn = wave & 3;          // 2 x 4 wave grid
    const int rl = lane & 15, kg = lane >> 4;
    const int z  = blockIdx.z;

    const __bf16* Ab = A + (long)z * ((EPI == 0) ? 0 : szA);
    const __bf16* Bb = B + (long)z * szB;

    // ---- staging: thread covers phys granules tid*16 and tid*16+8192 per half.
    // logical = phys ^ ((phys>>9 &1)<<5); +8192 preserves bit 9 -> row+64, col same.
    const int P    = tid * 16;
    const int Lg   = P ^ (((P >> 9) & 1) << 5);
    const int srow = Lg >> 7;          // 0..63
    const int scolb = Lg & 127;        // byte col within 128B row
    const long rbA = (long)ldA * 2;
    const long rbB = (long)ldB * 2;
    const char* gA = (const char*)Ab + ((long)blockIdx.x * 256 + srow) * rbA + scolb;
    const char* gB = (const char*)Bb + ((long)blockIdx.y * 256 + srow) * rbB + scolb;

    auto stageA = [&](int buf, int h, int kt) {
        const char* s = gA + (long)h * 128 * rbA + (long)kt * 128;
        char* d = lds + buf * 32768 + h * 16384 + wave * 1024;
        gl16(s, d);
        gl16(s + 64 * rbA, d + 8192);
    };
    auto stageB = [&](int buf, int h, int kt) {
        const char* s = gB + (long)h * 128 * rbB + (long)kt * 128;
        char* d = lds + 98304 + buf * 32768 + h * 16384 + wave * 1024;
        gl16(s, d);
        gl16(s + 64 * rbB, d + 8192);
    };

    // ---- fragment read offsets: row = (mi*16+rl), byte = row*128 + ks*64 + kg*16,
    // swizzled: bit9(=row bit2=(rl>>2)&1) flips bit5 (kg^=2).
    const int kgx16 = (kg ^ (((rl >> 2) & 1) << 1)) << 4;
    const int aoff = wm * 16384 + rl * 128 + kgx16;                       // +mi*2048+ks*64
    const int boff = (wn >> 1) * 16384 + ((wn & 1) * 64 + rl) * 128 + kgx16; // +ni*2048+ks*64

    // ---- prologue: tile0 (A+B) and A(1); wait tile0 (A(1)'s 4 loads may fly)
    stageA(0, 0, 0); stageA(0, 1, 0);
    stageB(0, 0, 0); stageB(0, 1, 0);
    if (Ktiles > 1) {
        stageA(1, 0, 1); stageA(1, 1, 1);
        asm volatile("s_waitcnt vmcnt(4)" ::: "memory");
    } else {
        asm volatile("s_waitcnt vmcnt(0)" ::: "memory");
    }
    BARRIER;

    f32x4 acc[8][4] = {};
    int ab = 0, bb = 0, as_ = 2;       // t%3, t&1, (t+2)%3

    for (int t = 0; t < Ktiles; ++t) {
        const char* rA = lds + ab * 32768;
        const char* rB = lds + 98304 + bb * 32768;
        const int sbb = bb ^ 1;
        bf16x8 a[4][2], b[4][2];

        // ---------------- phase 0: A[0-3]x2 + B[0-1]x2 reads; stage B0(t+1)
        #pragma unroll
        for (int mi = 0; mi < 4; ++mi)
            #pragma unroll
            for (int ks = 0; ks < 2; ++ks)
                a[mi][ks] = *(const bf16x8*)(rA + aoff + mi * 2048 + ks * 64);
        #pragma unroll
        for (int ni = 0; ni < 2; ++ni)
            #pragma unroll
            for (int ks = 0; ks < 2; ++ks)
                b[ni][ks] = *(const bf16x8*)(rB + boff + ni * 2048 + ks * 64);
        if (t + 1 < Ktiles) stageB(sbb, 0, t + 1);
        BARRIER;
        __builtin_amdgcn_s_setprio(1);
        #pragma unroll
        for (int mi = 0; mi < 4; ++mi)
            #pragma unroll
            for (int ni = 0; ni < 2; ++ni)
                #pragma unroll
                for (int ks = 0; ks < 2; ++ks)
                    acc[mi][ni] = __builtin_amdgcn_mfma_f32_16x16x32_bf16(
                        a[mi][ks], b[ni][ks], acc[mi][ni], 0, 0, 0);
        __builtin_amdgcn_s_setprio(0);
        BARRIER;

        // ---------------- phase 1: B[2-3]x2 reads; stage B1(t+1)
        #pragma unroll
        for (int ni = 2; ni < 4; ++ni)
            #pragma unroll
            for (int ks = 0; ks < 2; ++ks)
                b[ni][ks] = *(const bf16x8*)(rB + boff + ni * 2048 + ks * 64);
        if (t + 1 < Ktiles) stageB(sbb, 1, t + 1);
        BARRIER;
        __builtin_amdgcn_s_setprio(1);
        #pragma unroll
        for (int mi = 0; mi < 4; ++mi)
            #pragma unroll
            for (int ni = 2; ni < 4; ++ni)
                #pragma unroll
                for (int ks = 0; ks < 2; ++ks)
                    acc[mi][ni] = __builtin_amdgcn_mfma_f32_16x16x32_bf16(
                        a[mi][ks], b[ni][ks], acc[mi][ni], 0, 0, 0);
        __builtin_amdgcn_s_setprio(0);
        BARRIER;

        // ---------------- phase 2: A[4-7]x2 reads; stage A0(t+2)
        #pragma unroll
        for (int mi = 0; mi < 4; ++mi)
            #pragma unroll
            for (int ks = 0; ks < 2; ++ks)
                a[mi][ks] = *(const bf16x8*)(rA + aoff + (4 + mi) * 2048 + ks * 64);
        if (t + 2 < Ktiles) stageA(as_, 0, t + 2);
        BARRIER;
        __builtin_amdgcn_s_setprio(1);
        #pragma unroll
        for (int mi = 0; mi < 4; ++mi)
            #pragma unroll
            for (int ni = 0; ni < 2; ++ni)
                #pragma unroll
                for (int ks = 0; ks < 2; ++ks)
                    acc[4 + mi][ni] = __builtin_amdgcn_mfma_f32_16x16x32_bf16(
                        a[mi][ks], b[ni][ks], acc[4 + mi][ni], 0, 0, 0);
        __builtin_amdgcn_s_setprio(0);
        BARRIER;

        // ---------------- phase 3: no reads; stage A1(t+2); counted vmcnt
        if (t + 2 < Ktiles) stageA(as_, 1, t + 2);
        BARRIER;
        __builtin_amdgcn_s_setprio(1);
        #pragma unroll
        for (int mi = 0; mi < 4; ++mi)
            #pragma unroll
            for (int ni = 2; ni < 4; ++ni)
                #pragma unroll
                for (int ks = 0; ks < 2; ++ks)
                    acc[4 + mi][ni] = __builtin_amdgcn_mfma_f32_16x16x32_bf16(
                        a[mi][ks], b[ni][ks], acc[4 + mi][ni], 0, 0, 0);
        __builtin_amdgcn_s_setprio(0);
        if (t + 2 < Ktiles)      asm volatile("s_waitcnt vmcnt(4)" ::: "memory");
        else if (t + 1 < Ktiles) asm volatile("s_waitcnt vmcnt(0)" ::: "memory");
        BARRIER;

        ab = (ab == 2) ? 0 : ab + 1;
        bb ^= 1;
        as_ = (as_ == 2) ? 0 : as_ + 1;
    }

    // ---- epilogue (C/D layout: row = (lane>>4)*4+j, col = lane&15)
    const int rowg = blockIdx.x * 256 + wm * 128 + kg * 4;
    const int colg = blockIdx.y * 256 + wn * 64 + rl;

    if (EPI == 0) {
        __bf16* C = (__bf16*)C0 + (long)z * szC;
        const float* bbv = aux + (long)z * szAux;
        float bv[4];
        #pragma unroll
        for (int ni = 0; ni < 4; ++ni) bv[ni] = bbv[colg + ni * 16];
        #pragma unroll
        for (int mi = 0; mi < 8; ++mi)
            #pragma unroll
            for (int j = 0; j < 4; ++j) {
                __bf16* cr = C + (long)(rowg + mi * 16 + j) * ldC + colg;
                #pragma unroll
                for (int ni = 0; ni < 4; ++ni)
                    cr[ni * 16] = (__bf16)(acc[mi][ni][j] + bv[ni]);
            }
    } else if (EPI == 1) {
        __bf16* C = (__bf16*)C0 + (long)z * szC;
        float* wsum = (float*)lds;            // buffers dead after loop
        float rsm[8][4];
        #pragma unroll
        for (int mi = 0; mi < 8; ++mi)
            #pragma unroll
            for (int j = 0; j < 4; ++j) {
                float s = 0.f;
                __bf16* cr = C + (long)(rowg + mi * 16 + j) * ldC + colg;
                #pragma unroll
                for (int ni = 0; ni < 4; ++ni) {
                    float e = __expf(acc[mi][ni][j] * alpha);
                    cr[ni * 16] = (__bf16)e;
                    s += e;
                }
                rsm[mi][j] = s;
            }
        #pragma unroll
        for (int mi = 0; mi < 8; ++mi)
            #pragma unroll
            for (int j = 0; j < 4; ++j) {
                float s = rsm[mi][j];
                s += __shfl_xor(s, 1); s += __shfl_xor(s, 2);
                s += __shfl_xor(s, 4); s += __shfl_xor(s, 8);
                rsm[mi][j] = s;
            }
        if (rl == 0) {
            #pragma unroll
            for (int mi = 0; mi < 8; ++mi)
                #pragma unroll
                for (int j = 0; j < 4; ++j)
                    wsum[wn * 256 + wm * 128 + mi * 16 + kg * 4 + j] = rsm[mi][j];
        }
        __syncthreads();
        if (tid < 256) {
            float s = wsum[tid] + wsum[256 + tid] + wsum[512 + tid] + wsum[768 + tid];
            psum[(long)z * szPsum + (long)blockIdx.y * 4096 + blockIdx.x * 256 + tid] = s;
        }
    } else if (EPI == 2) {
        float* C = (float*)C0 + (long)z * szC;
        const float* rs = aux + (long)z * szAux;
        #pragma unroll
        for (int mi = 0; mi < 8; ++mi)
            #pragma unroll
            for (int j = 0; j < 4; ++j) {
                int r = rowg + mi * 16 + j;
                float inv = 1.f / rs[r];
                float* cr = C + (long)r * ldC + colg;
                #pragma unroll
                for (int ni = 0; ni < 4; ++ni) cr[ni * 16] = acc[mi][ni][j] * inv;
            }
    } else {
        float* C = (z < nkz - 1) ? ((float*)C0 + (long)z * szC) : (float*)C1;
        #pragma unroll
        for (int mi = 0; mi < 8; ++mi)
            #pragma unroll
            for (int j = 0; j < 4; ++j) {
                float* cr = C + (long)(rowg + mi * 16 + j) * ldC + colg;
                #pragma unroll
                for (int ni = 0; ni < 4; ++ni) cr[ni * 16] = acc[mi][ni][j];
            }
    }
}

// ---------------------------------------------------------------------------
// bf16 transpose: in [T][D] -> out [D][T], 64x64 tiles via LDS
// ---------------------------------------------------------------------------
__global__ __launch_bounds__(256)
void transpose64(const __bf16* __restrict__ in, __bf16* __restrict__ out,
                 int T, int D, long sIn, long sOut)
{
    __shared__ __bf16 tile[64][72];
    const __bf16* pin  = in  + (long)blockIdx.z * sIn;
    __bf16*       pout = out + (long)blockIdx.z * sOut;
    const int t0 = blockIdx.x * 64, d0 = blockIdx.y * 64;
    const int tid = threadIdx.x;
    const int rr = tid >> 3;
    const int cc = (tid & 7) * 8;

    #pragma unroll
    for (int it = 0; it < 2; ++it) {
        int r = rr + it * 32;
        bf16x8 v = *(const bf16x8*)(pin + (long)(t0 + r) * D + d0 + cc);
        *(bf16x8*)&tile[r][cc] = v;
    }
    __syncthreads();
    #pragma unroll
    for (int it = 0; it < 2; ++it) {
        int dr = rr + it * 32;
        bf16x8 o;
        #pragma unroll
        for (int j = 0; j < 8; ++j) o[j] = tile[cc + j][dr];
        *(bf16x8*)(pout + (long)(d0 + dr) * T + t0 + cc) = o;
    }
}

// rs[b][r] = sum_{cb<16} psum[b][cb][r]
__global__ __launch_bounds__(256)
void rowsum16(const float* __restrict__ psum, float* __restrict__ rs)
{
    int i = blockIdx.x * 256 + threadIdx.x;
    int b = i >> 12, r = i & 4095;
    const float* p = psum + (long)b * 65536 + r;
    float s = 0.f;
    #pragma unroll
    for (int cb = 0; cb < 16; ++cb) s += p[cb * 4096];
    rs[i] = s;
}

// out = (out + sum parts) / rs[row]
__global__ __launch_bounds__(256)
void pv_reduce(float* __restrict__ outb, const float* __restrict__ parts,
               int np, const float* __restrict__ rs)
{
    long i = ((long)blockIdx.x * 256 + threadIdx.x) * 4;
    f32x4 v = *(f32x4*)(outb + i);
    for (int p = 0; p < np; ++p)
        v += *(const f32x4*)(parts + (long)p * 4194304 + i);
    float inv = 1.f / rs[i >> 10];
    v *= inv;
    *(f32x4*)(outb + i) = v;
}

// ---------------------------------------------------------------------------
extern "C" void kernel_launch(void* const* d_in, const int* in_sizes, int n_in,
                              void* d_out, int out_size, void* d_ws, size_t ws_size,
                              hipStream_t stream)
{
    const float* x  = (const float*)d_in[0];
    const float* Wq = (const float*)d_in[1];
    const float* bq = (const float*)d_in[2];
    const float* Wk = (const float*)d_in[3];
    const float* bk = (const float*)d_in[4];
    const float* Wv = (const float*)d_in[5];
    const float* bv = (const float*)d_in[6];
    float* out = (float*)d_out;

    const long T = 4096, E = 1024, D = 1024;
    const long TD = T * D;
    const long TT = T * T;
    const long WB = D * E;
    const float ALPHA = 1.0f / 32.0f;
    char* W = (char*)d_ws;

    const size_t need_A  = 275853312;
    const size_t need_B2 = 191131648;

    if (ws_size >= need_A) {
        __bf16* wall = (__bf16*)(W);
        __bf16* xb   = (__bf16*)(W + 6291456);
        __bf16* vt   = (__bf16*)(W + 39845888);
        __bf16* q    = (__bf16*)(W + 73400320);
        __bf16* k    = (__bf16*)(W + 106954752);
        __bf16* P    = (__bf16*)(W + 140509184);
        float*  psum = (float*) (W + 274726912);
        float*  rs   = (float*) (W + 275775488);
        float*  bp   = (float*) (W + 275841024);

        pack_bias<<<12, 256, 0, stream>>>(bq, bk, bv, bp);
        cvt_f32_bf16<<<512, 256, 0, stream>>>(Wq, wall, WB/8);
        cvt_f32_bf16<<<512, 256, 0, stream>>>(Wk, wall + WB, WB/8);
        cvt_f32_bf16<<<512, 256, 0, stream>>>(Wv, wall + 2*WB, WB/8);
        cvt_f32_bf16<<<4096, 256, 0, stream>>>(x, xb, 4*TD/8);

        gemm8p<0><<<dim3(64,4,3), 512, 0, stream>>>(
            xb, wall, q, nullptr, bp, nullptr,
            1024, 1024, 1024, 16, 0, WB, 4*TD, 1024, 0, 0, 0.f);

        transpose64<<<dim3(64,16,4), 256, 0, stream>>>(P, vt, (int)T, (int)D, TD, TD);

        gemm8p<1><<<dim3(16,16,4), 512, 0, stream>>>(
            q, k, P, nullptr, nullptr, psum,
            1024, 1024, 4096, 16, TD, TD, TT, 0, 65536, 0, ALPHA);

        rowsum16<<<64, 256, 0, stream>>>(psum, rs);

        gemm8p<2><<<dim3(16,4,4), 512, 0, stream>>>(
            P, vt, out, nullptr, rs, nullptr,
            4096, 4096, 1024, 64, TT, TD, TD, 4096, 0, 0, 0.f);
    } else if (ws_size >= need_B2) {
        __bf16* wall  = (__bf16*)(W);
        __bf16* xb    = (__bf16*)(W + 6291456);
        float*  parts = (float*) (W + 6291456);
        __bf16* vt    = (__bf16*)(W + 56623104);
        __bf16* q     = (__bf16*)(W + 90177536);
        __bf16* k     = (__bf16*)(W + 123731968);
        __bf16* P     = (__bf16*)(W + 157286400);
        float*  psum  = (float*) (W + 190840832);
        float*  rs    = (float*) (W + 191102976);
        float*  bp    = (float*) (W + 191119360);

        pack_bias<<<12, 256, 0, stream>>>(bq, bk, bv, bp);
        cvt_f32_bf16<<<512, 256, 0, stream>>>(Wq, wall, WB/8);
        cvt_f32_bf16<<<512, 256, 0, stream>>>(Wk, wall + WB, WB/8);
        cvt_f32_bf16<<<512, 256, 0, stream>>>(Wv, wall + 2*WB, WB/8);
        cvt_f32_bf16<<<4096, 256, 0, stream>>>(x, xb, 4*TD/8);

        gemm8p<0><<<dim3(64,4,3), 512, 0, stream>>>(
            xb, wall, q, nullptr, bp, nullptr,
            1024, 1024, 1024, 16, 0, WB, 4*TD, 1024, 0, 0, 0.f);

        transpose64<<<dim3(64,16,4), 256, 0, stream>>>(P, vt, (int)T, (int)D, TD, TD);

        for (int b = 0; b < 4; ++b) {
            gemm8p<1><<<dim3(16,16,1), 512, 0, stream>>>(
                q + b*TD, k + b*TD, P, nullptr, nullptr, psum,
                1024, 1024, 4096, 16, 0, 0, 0, 0, 0, 0, ALPHA);
            rowsum16<<<16, 256, 0, stream>>>(psum, rs);
            gemm8p<3><<<dim3(16,4,4), 512, 0, stream>>>(
                P, vt + b*TD, parts, out + b*TD, nullptr, nullptr,
                4096, 4096, 1024, 16, 1024, 1024, TD, 0, 0, 4, 0.f);
            pv_reduce<<<4096, 256, 0, stream>>>(out + b*TD, parts, 3, rs);
        }
    } else {
        __bf16* wall  = (__bf16*)(W);
        __bf16* xb    = (__bf16*)(W + 6291456);
        float*  parts = (float*) (W + 6291456);
        __bf16* q     = (__bf16*)(W + 14680064);
        __bf16* k     = (__bf16*)(W + 23068672);
        __bf16* vt    = (__bf16*)(W + 31457280);
        __bf16* P     = (__bf16*)(W + 39845888);
        float*  psum  = (float*) (W + 73400320);
        float*  rs    = (float*) (W + 73662464);
        float*  bp    = (float*) (W + 73678848);

        pack_bias<<<12, 256, 0, stream>>>(bq, bk, bv, bp);
        cvt_f32_bf16<<<512, 256, 0, stream>>>(Wq, wall, WB/8);
        cvt_f32_bf16<<<512, 256, 0, stream>>>(Wk, wall + WB, WB/8);
        cvt_f32_bf16<<<512, 256, 0, stream>>>(Wv, wall + 2*WB, WB/8);

        for (int b = 0; b < 4; ++b) {
            cvt_f32_bf16<<<2048, 256, 0, stream>>>(x + b*TD, xb, TD/8);
            gemm8p<0><<<dim3(16,4,1), 512, 0, stream>>>(
                xb, wall, q, nullptr, bp, nullptr,
                1024, 1024, 1024, 16, 0, 0, 0, 0, 0, 0, 0.f);
            gemm8p<0><<<dim3(16,4,1), 512, 0, stream>>>(
                xb, wall + WB, k, nullptr, bp + 1024, nullptr,
                1024, 1024, 1024, 16, 0, 0, 0, 0, 0, 0, 0.f);
            gemm8p<0><<<dim3(16,4,1), 512, 0, stream>>>(
                xb, wall + 2*WB, P, nullptr, bp + 2048, nullptr,
                1024, 1024, 1024, 16, 0, 0, 0, 0, 0, 0, 0.f);
            transpose64<<<dim3(64,16,1), 256, 0, stream>>>(P, vt, (int)T, (int)D, 0, 0);
            gemm8p<1><<<dim3(16,16,1), 512, 0, stream>>>(
                q, k, P, nullptr, nullptr, psum,
                1024, 1024, 4096, 16, 0, 0, 0, 0, 0, 0, ALPHA);
            rowsum16<<<16, 256, 0, stream>>>(psum, rs);
            gemm8p<3><<<dim3(16,4,2), 512, 0, stream>>>(
                P, vt, parts, out + b*TD, nullptr, nullptr,
                4096, 4096, 1024, 32, 2048, 2048, TD, 0, 0, 2, 0.f);
            pv_reduce<<<4096, 256, 0, stream>>>(out + b*TD, parts, 1, rs);
        }
    }
}

// Round 4
// 518.805 us; speedup vs baseline: 1.6375x; 1.0659x over previous
//
#include <hip/hip_runtime.h>
#include <hip/hip_bf16.h>

typedef __bf16 bf16x8 __attribute__((ext_vector_type(8)));
typedef float  f32x4  __attribute__((ext_vector_type(4)));

typedef __attribute__((address_space(1))) const void* as1p;
typedef __attribute__((address_space(3))) void*       as3p;

__device__ __forceinline__ void gl16(const void* g, void* l) {
    __builtin_amdgcn_global_load_lds((as1p)g, (as3p)l, 16, 0, 0);
}
#define MEMFENCE asm volatile("" ::: "memory")
#define BARRIER  do { MEMFENCE; __builtin_amdgcn_s_barrier(); MEMFENCE; } while (0)

// ---------------------------------------------------------------------------
// fp32 -> bf16 convert, 8 elements/thread, grid-stride
// ---------------------------------------------------------------------------
__global__ __launch_bounds__(256)
void cvt_f32_bf16(const float* __restrict__ in, __bf16* __restrict__ out, long n8)
{
    long i = (long)blockIdx.x * blockDim.x + threadIdx.x;
    const long stride = (long)gridDim.x * blockDim.x;
    for (; i < n8; i += stride) {
        f32x4 a = ((const f32x4*)in)[2*i];
        f32x4 b = ((const f32x4*)in)[2*i + 1];
        bf16x8 o;
        #pragma unroll
        for (int j = 0; j < 4; ++j) { o[j] = (__bf16)a[j]; o[4+j] = (__bf16)b[j]; }
        ((bf16x8*)out)[i] = o;
    }
}

__global__ __launch_bounds__(256)
void pack_bias(const float* __restrict__ a, const float* __restrict__ b,
               const float* __restrict__ c, float* __restrict__ o)
{
    int i = blockIdx.x * 256 + threadIdx.x;   // 3072 total
    const float* s = (i < 1024) ? a : (i < 2048) ? b : c;
    o[i] = s[i & 1023];
}

// ---------------------------------------------------------------------------
// 256x256-tile NT GEMM, BK=64, 8 waves (2Mx4N).
// LDS: A ring 3 x 32KB @0, B ring 2 x 32KB @98304 (160 KB total).
// Free-flow schedule: NO intra-tile barriers — ds_reads, staging and MFMAs
// overlap via the compiler scoreboard; one counted vmcnt + one barrier per
// K-tile (stage targets A(t+2)/B(t+1), safe for any wave skewed <1 tile).
// EPI 0: +bias[col], bf16 out (z = weight)   EPI 1: exp(acc*alpha) + row psums
// EPI 2: f32 out / rowsum                    EPI 3: split-K f32 partials
// ---------------------------------------------------------------------------
template<int EPI>
__global__ __launch_bounds__(512, 2)
void gemm8p(const __bf16* __restrict__ A, const __bf16* __restrict__ B,
            void* __restrict__ C0, void* __restrict__ C1,
            const float* __restrict__ aux, float* __restrict__ psum,
            int ldA, int ldB, int ldC, int Ktiles,
            long szA, long szB, long szC, long szAux, long szPsum,
            int nkz, float alpha)
{
    __shared__ char lds[163840];

    const int tid  = threadIdx.x;
    const int wave = tid >> 6, lane = tid & 63;
    const int wm = wave >> 2, wn = wave & 3;          // 2 x 4 wave grid
    const int rl = lane & 15, kg = lane >> 4;
    const int z  = blockIdx.z;

    const __bf16* Ab = A + (long)z * ((EPI == 0) ? 0 : szA);
    const __bf16* Bb = B + (long)z * szB;

    // ---- staging: thread covers phys granules tid*16 and tid*16+8192 per half.
    // logical = phys ^ ((phys>>9 &1)<<5); +8192 preserves bit 9 -> row+64, col same.
    const int P    = tid * 16;
    const int Lg   = P ^ (((P >> 9) & 1) << 5);
    const int srow = Lg >> 7;          // 0..63
    const int scolb = Lg & 127;        // byte col within 128B row
    const long rbA = (long)ldA * 2;
    const long rbB = (long)ldB * 2;
    const char* gA = (const char*)Ab + ((long)blockIdx.x * 256 + srow) * rbA + scolb;
    const char* gB = (const char*)Bb + ((long)blockIdx.y * 256 + srow) * rbB + scolb;

    auto stageA = [&](int buf, int h, int kt) {
        const char* s = gA + (long)h * 128 * rbA + (long)kt * 128;
        char* d = lds + buf * 32768 + h * 16384 + wave * 1024;
        gl16(s, d);
        gl16(s + 64 * rbA, d + 8192);
    };
    auto stageB = [&](int buf, int h, int kt) {
        const char* s = gB + (long)h * 128 * rbB + (long)kt * 128;
        char* d = lds + 98304 + buf * 32768 + h * 16384 + wave * 1024;
        gl16(s, d);
        gl16(s + 64 * rbB, d + 8192);
    };

    // ---- fragment read offsets: row = (mi*16+rl), byte = row*128 + ks*64 + kg*16,
    // swizzled: bit9(=row bit2=(rl>>2)&1) flips bit5 (kg^=2).
    const int kgx16 = (kg ^ (((rl >> 2) & 1) << 1)) << 4;
    const int aoff = wm * 16384 + rl * 128 + kgx16;                       // +mi*2048+ks*64
    const int boff = (wn >> 1) * 16384 + ((wn & 1) * 64 + rl) * 128 + kgx16; // +ni*2048+ks*64

    // ---- prologue: tile0 (A+B) and A(1); wait tile0 (A(1)'s 4 loads may fly)
    stageA(0, 0, 0); stageA(0, 1, 0);
    stageB(0, 0, 0); stageB(0, 1, 0);
    if (Ktiles > 1) {
        stageA(1, 0, 1); stageA(1, 1, 1);
        asm volatile("s_waitcnt vmcnt(4)" ::: "memory");
    } else {
        asm volatile("s_waitcnt vmcnt(0)" ::: "memory");
    }
    BARRIER;

    f32x4 acc[8][4] = {};
    int ab = 0, bb = 0, as_ = 2;       // t%3, t&1, (t+2)%3

    for (int t = 0; t < Ktiles; ++t) {
        const char* rA = lds + ab * 32768;
        const char* rB = lds + 98304 + bb * 32768;
        const int sbb = bb ^ 1;
        bf16x8 a[4][2], b[4][2];

        // reads: A rows 0-3 + all B (16 b128); stage next-tile B
        #pragma unroll
        for (int mi = 0; mi < 4; ++mi)
            #pragma unroll
            for (int ks = 0; ks < 2; ++ks)
                a[mi][ks] = *(const bf16x8*)(rA + aoff + mi * 2048 + ks * 64);
        #pragma unroll
        for (int ni = 0; ni < 4; ++ni)
            #pragma unroll
            for (int ks = 0; ks < 2; ++ks)
                b[ni][ks] = *(const bf16x8*)(rB + boff + ni * 2048 + ks * 64);
        if (t + 1 < Ktiles) { stageB(sbb, 0, t + 1); stageB(sbb, 1, t + 1); }

        // MFMA upper half (acc rows 0-3)
        #pragma unroll
        for (int mi = 0; mi < 4; ++mi)
            #pragma unroll
            for (int ni = 0; ni < 4; ++ni)
                #pragma unroll
                for (int ks = 0; ks < 2; ++ks)
                    acc[mi][ni] = __builtin_amdgcn_mfma_f32_16x16x32_bf16(
                        a[mi][ks], b[ni][ks], acc[mi][ni], 0, 0, 0);

        // reads: A rows 4-7 (reuse a); stage A(t+2)
        #pragma unroll
        for (int mi = 0; mi < 4; ++mi)
            #pragma unroll
            for (int ks = 0; ks < 2; ++ks)
                a[mi][ks] = *(const bf16x8*)(rA + aoff + (4 + mi) * 2048 + ks * 64);
        if (t + 2 < Ktiles) { stageA(as_, 0, t + 2); stageA(as_, 1, t + 2); }

        // MFMA lower half (acc rows 4-7)
        #pragma unroll
        for (int mi = 0; mi < 4; ++mi)
            #pragma unroll
            for (int ni = 0; ni < 4; ++ni)
                #pragma unroll
                for (int ks = 0; ks < 2; ++ks)
                    acc[4 + mi][ni] = __builtin_amdgcn_mfma_f32_16x16x32_bf16(
                        a[mi][ks], b[ni][ks], acc[4 + mi][ni], 0, 0, 0);

        // per-tile counted wait + single barrier (skip after last tile)
        if (t + 2 < Ktiles)      asm volatile("s_waitcnt vmcnt(4)" ::: "memory");
        else if (t + 1 < Ktiles) asm volatile("s_waitcnt vmcnt(0)" ::: "memory");
        if (t + 1 < Ktiles) BARRIER;

        ab = (ab == 2) ? 0 : ab + 1;
        bb ^= 1;
        as_ = (as_ == 2) ? 0 : as_ + 1;
    }

    // ---- epilogue (C/D layout: row = (lane>>4)*4+j, col = lane&15)
    const int rowg = blockIdx.x * 256 + wm * 128 + kg * 4;
    const int colg = blockIdx.y * 256 + wn * 64 + rl;

    if (EPI == 0) {
        __bf16* C = (__bf16*)C0 + (long)z * szC;
        const float* bbv = aux + (long)z * szAux;
        float bv[4];
        #pragma unroll
        for (int ni = 0; ni < 4; ++ni) bv[ni] = bbv[colg + ni * 16];
        #pragma unroll
        for (int mi = 0; mi < 8; ++mi)
            #pragma unroll
            for (int j = 0; j < 4; ++j) {
                __bf16* cr = C + (long)(rowg + mi * 16 + j) * ldC + colg;
                #pragma unroll
                for (int ni = 0; ni < 4; ++ni)
                    cr[ni * 16] = (__bf16)(acc[mi][ni][j] + bv[ni]);
            }
    } else if (EPI == 1) {
        BARRIER;                               // LDS about to be reused (wsum)
        __bf16* C = (__bf16*)C0 + (long)z * szC;
        float* wsum = (float*)lds;
        float rsm[8][4];
        #pragma unroll
        for (int mi = 0; mi < 8; ++mi)
            #pragma unroll
            for (int j = 0; j < 4; ++j) {
                float s = 0.f;
                __bf16* cr = C + (long)(rowg + mi * 16 + j) * ldC + colg;
                #pragma unroll
                for (int ni = 0; ni < 4; ++ni) {
                    float e = __expf(acc[mi][ni][j] * alpha);
                    cr[ni * 16] = (__bf16)e;
                    s += e;
                }
                rsm[mi][j] = s;
            }
        #pragma unroll
        for (int mi = 0; mi < 8; ++mi)
            #pragma unroll
            for (int j = 0; j < 4; ++j) {
                float s = rsm[mi][j];
                s += __shfl_xor(s, 1); s += __shfl_xor(s, 2);
                s += __shfl_xor(s, 4); s += __shfl_xor(s, 8);
                rsm[mi][j] = s;
            }
        if (rl == 0) {
            #pragma unroll
            for (int mi = 0; mi < 8; ++mi)
                #pragma unroll
                for (int j = 0; j < 4; ++j)
                    wsum[wn * 256 + wm * 128 + mi * 16 + kg * 4 + j] = rsm[mi][j];
        }
        __syncthreads();
        if (tid < 256) {
            float s = wsum[tid] + wsum[256 + tid] + wsum[512 + tid] + wsum[768 + tid];
            psum[(long)z * szPsum + (long)blockIdx.y * 4096 + blockIdx.x * 256 + tid] = s;
        }
    } else if (EPI == 2) {
        float* C = (float*)C0 + (long)z * szC;
        const float* rs = aux + (long)z * szAux;
        #pragma unroll
        for (int mi = 0; mi < 8; ++mi)
            #pragma unroll
            for (int j = 0; j < 4; ++j) {
                int r = rowg + mi * 16 + j;
                float inv = 1.f / rs[r];
                float* cr = C + (long)r * ldC + colg;
                #pragma unroll
                for (int ni = 0; ni < 4; ++ni) cr[ni * 16] = acc[mi][ni][j] * inv;
            }
    } else {
        float* C = (z < nkz - 1) ? ((float*)C0 + (long)z * szC) : (float*)C1;
        #pragma unroll
        for (int mi = 0; mi < 8; ++mi)
            #pragma unroll
            for (int j = 0; j < 4; ++j) {
                float* cr = C + (long)(rowg + mi * 16 + j) * ldC + colg;
                #pragma unroll
                for (int ni = 0; ni < 4; ++ni) cr[ni * 16] = acc[mi][ni][j];
            }
    }
}

// ---------------------------------------------------------------------------
// bf16 transpose: in [T][D] -> out [D][T], 64x64 tiles via LDS
// ---------------------------------------------------------------------------
__global__ __launch_bounds__(256)
void transpose64(const __bf16* __restrict__ in, __bf16* __restrict__ out,
                 int T, int D, long sIn, long sOut)
{
    __shared__ __bf16 tile[64][72];
    const __bf16* pin  = in  + (long)blockIdx.z * sIn;
    __bf16*       pout = out + (long)blockIdx.z * sOut;
    const int t0 = blockIdx.x * 64, d0 = blockIdx.y * 64;
    const int tid = threadIdx.x;
    const int rr = tid >> 3;
    const int cc = (tid & 7) * 8;

    #pragma unroll
    for (int it = 0; it < 2; ++it) {
        int r = rr + it * 32;
        bf16x8 v = *(const bf16x8*)(pin + (long)(t0 + r) * D + d0 + cc);
        *(bf16x8*)&tile[r][cc] = v;
    }
    __syncthreads();
    #pragma unroll
    for (int it = 0; it < 2; ++it) {
        int dr = rr + it * 32;
        bf16x8 o;
        #pragma unroll
        for (int j = 0; j < 8; ++j) o[j] = tile[cc + j][dr];
        *(bf16x8*)(pout + (long)(d0 + dr) * T + t0 + cc) = o;
    }
}

// rs[b][r] = sum_{cb<16} psum[b][cb][r]
__global__ __launch_bounds__(256)
void rowsum16(const float* __restrict__ psum, float* __restrict__ rs)
{
    int i = blockIdx.x * 256 + threadIdx.x;
    int b = i >> 12, r = i & 4095;
    const float* p = psum + (long)b * 65536 + r;
    float s = 0.f;
    #pragma unroll
    for (int cb = 0; cb < 16; ++cb) s += p[cb * 4096];
    rs[i] = s;
}

// out = (out + sum parts) / rs[row]
__global__ __launch_bounds__(256)
void pv_reduce(float* __restrict__ outb, const float* __restrict__ parts,
               int np, const float* __restrict__ rs)
{
    long i = ((long)blockIdx.x * 256 + threadIdx.x) * 4;
    f32x4 v = *(f32x4*)(outb + i);
    for (int p = 0; p < np; ++p)
        v += *(const f32x4*)(parts + (long)p * 4194304 + i);
    float inv = 1.f / rs[i >> 10];
    v *= inv;
    *(f32x4*)(outb + i) = v;
}

// ---------------------------------------------------------------------------
extern "C" void kernel_launch(void* const* d_in, const int* in_sizes, int n_in,
                              void* d_out, int out_size, void* d_ws, size_t ws_size,
                              hipStream_t stream)
{
    const float* x  = (const float*)d_in[0];
    const float* Wq = (const float*)d_in[1];
    const float* bq = (const float*)d_in[2];
    const float* Wk = (const float*)d_in[3];
    const float* bk = (const float*)d_in[4];
    const float* Wv = (const float*)d_in[5];
    const float* bv = (const float*)d_in[6];
    float* out = (float*)d_out;

    const long T = 4096, E = 1024, D = 1024;
    const long TD = T * D;
    const long TT = T * T;
    const long WB = D * E;
    const float ALPHA = 1.0f / 32.0f;
    char* W = (char*)d_ws;

    const size_t need_A  = 275853312;
    const size_t need_B2 = 191131648;

    if (ws_size >= need_A) {
        __bf16* wall = (__bf16*)(W);
        __bf16* xb   = (__bf16*)(W + 6291456);
        __bf16* vt   = (__bf16*)(W + 39845888);
        __bf16* q    = (__bf16*)(W + 73400320);
        __bf16* k    = (__bf16*)(W + 106954752);
        __bf16* P    = (__bf16*)(W + 140509184);
        float*  psum = (float*) (W + 274726912);
        float*  rs   = (float*) (W + 275775488);
        float*  bp   = (float*) (W + 275841024);

        pack_bias<<<12, 256, 0, stream>>>(bq, bk, bv, bp);
        cvt_f32_bf16<<<512, 256, 0, stream>>>(Wq, wall, WB/8);
        cvt_f32_bf16<<<512, 256, 0, stream>>>(Wk, wall + WB, WB/8);
        cvt_f32_bf16<<<512, 256, 0, stream>>>(Wv, wall + 2*WB, WB/8);
        cvt_f32_bf16<<<4096, 256, 0, stream>>>(x, xb, 4*TD/8);

        gemm8p<0><<<dim3(64,4,3), 512, 0, stream>>>(
            xb, wall, q, nullptr, bp, nullptr,
            1024, 1024, 1024, 16, 0, WB, 4*TD, 1024, 0, 0, 0.f);

        transpose64<<<dim3(64,16,4), 256, 0, stream>>>(P, vt, (int)T, (int)D, TD, TD);

        gemm8p<1><<<dim3(16,16,4), 512, 0, stream>>>(
            q, k, P, nullptr, nullptr, psum,
            1024, 1024, 4096, 16, TD, TD, TT, 0, 65536, 0, ALPHA);

        rowsum16<<<64, 256, 0, stream>>>(psum, rs);

        gemm8p<2><<<dim3(16,4,4), 512, 0, stream>>>(
            P, vt, out, nullptr, rs, nullptr,
            4096, 4096, 1024, 64, TT, TD, TD, 4096, 0, 0, 0.f);
    } else if (ws_size >= need_B2) {
        __bf16* wall  = (__bf16*)(W);
        __bf16* xb    = (__bf16*)(W + 6291456);
        float*  parts = (float*) (W + 6291456);
        __bf16* vt    = (__bf16*)(W + 56623104);
        __bf16* q     = (__bf16*)(W + 90177536);
        __bf16* k     = (__bf16*)(W + 123731968);
        __bf16* P     = (__bf16*)(W + 157286400);
        float*  psum  = (float*) (W + 190840832);
        float*  rs    = (float*) (W + 191102976);
        float*  bp    = (float*) (W + 191119360);

        pack_bias<<<12, 256, 0, stream>>>(bq, bk, bv, bp);
        cvt_f32_bf16<<<512, 256, 0, stream>>>(Wq, wall, WB/8);
        cvt_f32_bf16<<<512, 256, 0, stream>>>(Wk, wall + WB, WB/8);
        cvt_f32_bf16<<<512, 256, 0, stream>>>(Wv, wall + 2*WB, WB/8);
        cvt_f32_bf16<<<4096, 256, 0, stream>>>(x, xb, 4*TD/8);

        gemm8p<0><<<dim3(64,4,3), 512, 0, stream>>>(
            xb, wall, q, nullptr, bp, nullptr,
            1024, 1024, 1024, 16, 0, WB, 4*TD, 1024, 0, 0, 0.f);

        transpose64<<<dim3(64,16,4), 256, 0, stream>>>(P, vt, (int)T, (int)D, TD, TD);

        for (int b = 0; b < 4; ++b) {
            gemm8p<1><<<dim3(16,16,1), 512, 0, stream>>>(
                q + b*TD, k + b*TD, P, nullptr, nullptr, psum,
                1024, 1024, 4096, 16, 0, 0, 0, 0, 0, 0, ALPHA);
            rowsum16<<<16, 256, 0, stream>>>(psum, rs);
            gemm8p<3><<<dim3(16,4,4), 512, 0, stream>>>(
                P, vt + b*TD, parts, out + b*TD, nullptr, nullptr,
                4096, 4096, 1024, 16, 1024, 1024, TD, 0, 0, 4, 0.f);
            pv_reduce<<<4096, 256, 0, stream>>>(out + b*TD, parts, 3, rs);
        }
    } else {
        __bf16* wall  = (__bf16*)(W);
        __bf16* xb    = (__bf16*)(W + 6291456);
        float*  parts = (float*) (W + 6291456);
        __bf16* q     = (__bf16*)(W + 14680064);
        __bf16* k     = (__bf16*)(W + 23068672);
        __bf16* vt    = (__bf16*)(W + 31457280);
        __bf16* P     = (__bf16*)(W + 39845888);
        float*  psum  = (float*) (W + 73400320);
        float*  rs    = (float*) (W + 73662464);
        float*  bp    = (float*) (W + 73678848);

        pack_bias<<<12, 256, 0, stream>>>(bq, bk, bv, bp);
        cvt_f32_bf16<<<512, 256, 0, stream>>>(Wq, wall, WB/8);
        cvt_f32_bf16<<<512, 256, 0, stream>>>(Wk, wall + WB, WB/8);
        cvt_f32_bf16<<<512, 256, 0, stream>>>(Wv, wall + 2*WB, WB/8);

        for (int b = 0; b < 4; ++b) {
            cvt_f32_bf16<<<2048, 256, 0, stream>>>(x + b*TD, xb, TD/8);
            gemm8p<0><<<dim3(16,4,1), 512, 0, stream>>>(
                xb, wall, q, nullptr, bp, nullptr,
                1024, 1024, 1024, 16, 0, 0, 0, 0, 0, 0, 0.f);
            gemm8p<0><<<dim3(16,4,1), 512, 0, stream>>>(
                xb, wall + WB, k, nullptr, bp + 1024, nullptr,
                1024, 1024, 1024, 16, 0, 0, 0, 0, 0, 0, 0.f);
            gemm8p<0><<<dim3(16,4,1), 512, 0, stream>>>(
                xb, wall + 2*WB, P, nullptr, bp + 2048, nullptr,
                1024, 1024, 1024, 16, 0, 0, 0, 0, 0, 0, 0.f);
            transpose64<<<dim3(64,16,1), 256, 0, stream>>>(P, vt, (int)T, (int)D, 0, 0);
            gemm8p<1><<<dim3(16,16,1), 512, 0, stream>>>(
                q, k, P, nullptr, nullptr, psum,
                1024, 1024, 4096, 16, 0, 0, 0, 0, 0, 0, ALPHA);
            rowsum16<<<16, 256, 0, stream>>>(psum, rs);
            gemm8p<3><<<dim3(16,4,2), 512, 0, stream>>>(
                P, vt, parts, out + b*TD, nullptr, nullptr,
                4096, 4096, 1024, 32, 2048, 2048, TD, 0, 0, 2, 0.f);
            pv_reduce<<<4096, 256, 0, stream>>>(out + b*TD, parts, 1, rs);
        }
    }
}

// Round 5
// 509.182 us; speedup vs baseline: 1.6685x; 1.0189x over previous
//
#include <hip/hip_runtime.h>
#include <hip/hip_bf16.h>

typedef __bf16 bf16x8 __attribute__((ext_vector_type(8)));
typedef float  f32x4  __attribute__((ext_vector_type(4)));

typedef __attribute__((address_space(1))) const void* as1p;
typedef __attribute__((address_space(3))) void*       as3p;

__device__ __forceinline__ void gl16(const void* g, void* l) {
    __builtin_amdgcn_global_load_lds((as1p)g, (as3p)l, 16, 0, 0);
}
#define MEMFENCE asm volatile("" ::: "memory")
#define BARRIER  do { MEMFENCE; __builtin_amdgcn_s_barrier(); MEMFENCE; } while (0)

// ---------------------------------------------------------------------------
// fp32 -> bf16 convert, 8 elements/thread, grid-stride
// ---------------------------------------------------------------------------
__global__ __launch_bounds__(256)
void cvt_f32_bf16(const float* __restrict__ in, __bf16* __restrict__ out, long n8)
{
    long i = (long)blockIdx.x * blockDim.x + threadIdx.x;
    const long stride = (long)gridDim.x * blockDim.x;
    for (; i < n8; i += stride) {
        f32x4 a = ((const f32x4*)in)[2*i];
        f32x4 b = ((const f32x4*)in)[2*i + 1];
        bf16x8 o;
        #pragma unroll
        for (int j = 0; j < 4; ++j) { o[j] = (__bf16)a[j]; o[4+j] = (__bf16)b[j]; }
        ((bf16x8*)out)[i] = o;
    }
}

__global__ __launch_bounds__(256)
void pack_bias(const float* __restrict__ a, const float* __restrict__ b,
               const float* __restrict__ c, float* __restrict__ o)
{
    int i = blockIdx.x * 256 + threadIdx.x;   // 3072 total
    const float* s = (i < 1024) ? a : (i < 2048) ? b : c;
    o[i] = s[i & 1023];
}

// ---------------------------------------------------------------------------
// 256x256-tile NT GEMM, BK=64, 8 waves (2Mx4N).
// LDS: A ring 3 x 32KB @0, B ring 2 x 32KB @98304 (160 KB total).
// Swizzle (involution on bits 4-6, row = byte>>7 within each 16KB half):
//   phys = logical ^ ((row & 7) << 4)
// giving every lane-octet 8 distinct 16B bank slots (conflict-free b128).
// Free-flow schedule: no intra-tile barriers; one counted vmcnt + one
// barrier per K-tile (stage targets A(t+2)/B(t+1), safe for skew < 1 tile).
// EPI 0: +bias[col], bf16 out (z = weight)   EPI 1: exp(acc*alpha) + row psums
// EPI 2: f32 out / rowsum                    EPI 3: split-K f32 partials
// ---------------------------------------------------------------------------
template<int EPI>
__global__ __launch_bounds__(512, 2)
void gemm8p(const __bf16* __restrict__ A, const __bf16* __restrict__ B,
            void* __restrict__ C0, void* __restrict__ C1,
            const float* __restrict__ aux, float* __restrict__ psum,
            int ldA, int ldB, int ldC, int Ktiles,
            long szA, long szB, long szC, long szAux, long szPsum,
            int nkz, float alpha)
{
    __shared__ char lds[163840];

    const int tid  = threadIdx.x;
    const int wave = tid >> 6, lane = tid & 63;
    const int wm = wave >> 2, wn = wave & 3;          // 2 x 4 wave grid
    const int rl = lane & 15, kg = lane >> 4;
    const int z  = blockIdx.z;

    const __bf16* Ab = A + (long)z * ((EPI == 0) ? 0 : szA);
    const __bf16* Bb = B + (long)z * szB;

    // ---- staging: thread covers phys granules P=tid*16 and P+8192 per half.
    // logical col = (P & 127) ^ ((row & 7) << 4); row = P>>7 (XOR keeps row).
    const int P     = tid * 16;
    const int srow  = P >> 7;                         // 0..63
    const int scolb = (P & 127) ^ ((srow & 7) << 4);  // byte col in 128B row
    const long rbA = (long)ldA * 2;
    const long rbB = (long)ldB * 2;
    const char* gA = (const char*)Ab + ((long)blockIdx.x * 256 + srow) * rbA + scolb;
    const char* gB = (const char*)Bb + ((long)blockIdx.y * 256 + srow) * rbB + scolb;

    auto stageA = [&](int buf, int h, int kt) {
        const char* s = gA + (long)h * 128 * rbA + (long)kt * 128;
        char* d = lds + buf * 32768 + h * 16384 + wave * 1024;
        gl16(s, d);
        gl16(s + 64 * rbA, d + 8192);
    };
    auto stageB = [&](int buf, int h, int kt) {
        const char* s = gB + (long)h * 128 * rbB + (long)kt * 128;
        char* d = lds + 98304 + buf * 32768 + h * 16384 + wave * 1024;
        gl16(s, d);
        gl16(s + 64 * rbB, d + 8192);
    };

    // ---- fragment reads: logical byte = row*128 + ks*64 + kg*16,
    // row = (mi|ni)*16 + rl (row&7 == rl&7)  ->  phys col XOR (rl&7)<<4.
    const int csw[2] = { (kg << 4) ^ ((rl & 7) << 4),
                         ((kg << 4) ^ ((rl & 7) << 4)) ^ 64 };
    const int aoff = wm * 16384 + rl * 128;                      // + mi*2048 + csw[ks]
    const int boff = (wn >> 1) * 16384 + ((wn & 1) * 64 + rl) * 128; // + ni*2048 + csw[ks]

    // ---- prologue: tile0 (A+B) and A(1); wait tile0 (A(1)'s 4 loads may fly)
    stageA(0, 0, 0); stageA(0, 1, 0);
    stageB(0, 0, 0); stageB(0, 1, 0);
    if (Ktiles > 1) {
        stageA(1, 0, 1); stageA(1, 1, 1);
        asm volatile("s_waitcnt vmcnt(4)" ::: "memory");
    } else {
        asm volatile("s_waitcnt vmcnt(0)" ::: "memory");
    }
    BARRIER;

    f32x4 acc[8][4] = {};
    int ab = 0, bb = 0, as_ = 2;       // t%3, t&1, (t+2)%3

    for (int t = 0; t < Ktiles; ++t) {
        const char* rA = lds + ab * 32768;
        const char* rB = lds + 98304 + bb * 32768;
        const int sbb = bb ^ 1;
        bf16x8 a[4][2], b[4][2];

        // reads: A rows 0-3 + all B (16 b128); stage next-tile B
        #pragma unroll
        for (int mi = 0; mi < 4; ++mi)
            #pragma unroll
            for (int ks = 0; ks < 2; ++ks)
                a[mi][ks] = *(const bf16x8*)(rA + aoff + mi * 2048 + csw[ks]);
        #pragma unroll
        for (int ni = 0; ni < 4; ++ni)
            #pragma unroll
            for (int ks = 0; ks < 2; ++ks)
                b[ni][ks] = *(const bf16x8*)(rB + boff + ni * 2048 + csw[ks]);
        if (t + 1 < Ktiles) { stageB(sbb, 0, t + 1); stageB(sbb, 1, t + 1); }

        // MFMA upper half (acc rows 0-3)
        #pragma unroll
        for (int mi = 0; mi < 4; ++mi)
            #pragma unroll
            for (int ni = 0; ni < 4; ++ni)
                #pragma unroll
                for (int ks = 0; ks < 2; ++ks)
                    acc[mi][ni] = __builtin_amdgcn_mfma_f32_16x16x32_bf16(
                        a[mi][ks], b[ni][ks], acc[mi][ni], 0, 0, 0);

        // reads: A rows 4-7 (reuse a); stage A(t+2)
        #pragma unroll
        for (int mi = 0; mi < 4; ++mi)
            #pragma unroll
            for (int ks = 0; ks < 2; ++ks)
                a[mi][ks] = *(const bf16x8*)(rA + aoff + (4 + mi) * 2048 + csw[ks]);
        if (t + 2 < Ktiles) { stageA(as_, 0, t + 2); stageA(as_, 1, t + 2); }

        // MFMA lower half (acc rows 4-7)
        #pragma unroll
        for (int mi = 0; mi < 4; ++mi)
            #pragma unroll
            for (int ni = 0; ni < 4; ++ni)
                #pragma unroll
                for (int ks = 0; ks < 2; ++ks)
                    acc[4 + mi][ni] = __builtin_amdgcn_mfma_f32_16x16x32_bf16(
                        a[mi][ks], b[ni][ks], acc[4 + mi][ni], 0, 0, 0);

        // per-tile counted wait + single barrier (skip after last tile)
        if (t + 2 < Ktiles)      asm volatile("s_waitcnt vmcnt(4)" ::: "memory");
        else if (t + 1 < Ktiles) asm volatile("s_waitcnt vmcnt(0)" ::: "memory");
        if (t + 1 < Ktiles) BARRIER;

        ab = (ab == 2) ? 0 : ab + 1;
        bb ^= 1;
        as_ = (as_ == 2) ? 0 : as_ + 1;
    }

    // ---- epilogue (C/D layout: row = (lane>>4)*4+j, col = lane&15)
    const int rowg = blockIdx.x * 256 + wm * 128 + kg * 4;
    const int colg = blockIdx.y * 256 + wn * 64 + rl;

    if (EPI == 0) {
        __bf16* C = (__bf16*)C0 + (long)z * szC;
        const float* bbv = aux + (long)z * szAux;
        float bv[4];
        #pragma unroll
        for (int ni = 0; ni < 4; ++ni) bv[ni] = bbv[colg + ni * 16];
        #pragma unroll
        for (int mi = 0; mi < 8; ++mi)
            #pragma unroll
            for (int j = 0; j < 4; ++j) {
                __bf16* cr = C + (long)(rowg + mi * 16 + j) * ldC + colg;
                #pragma unroll
                for (int ni = 0; ni < 4; ++ni)
                    cr[ni * 16] = (__bf16)(acc[mi][ni][j] + bv[ni]);
            }
    } else if (EPI == 1) {
        BARRIER;                               // LDS about to be reused (wsum)
        __bf16* C = (__bf16*)C0 + (long)z * szC;
        float* wsum = (float*)lds;
        float rsm[8][4];
        #pragma unroll
        for (int mi = 0; mi < 8; ++mi)
            #pragma unroll
            for (int j = 0; j < 4; ++j) {
                float s = 0.f;
                __bf16* cr = C + (long)(rowg + mi * 16 + j) * ldC + colg;
                #pragma unroll
                for (int ni = 0; ni < 4; ++ni) {
                    float e = __expf(acc[mi][ni][j] * alpha);
                    cr[ni * 16] = (__bf16)e;
                    s += e;
                }
                rsm[mi][j] = s;
            }
        #pragma unroll
        for (int mi = 0; mi < 8; ++mi)
            #pragma unroll
            for (int j = 0; j < 4; ++j) {
                float s = rsm[mi][j];
                s += __shfl_xor(s, 1); s += __shfl_xor(s, 2);
                s += __shfl_xor(s, 4); s += __shfl_xor(s, 8);
                rsm[mi][j] = s;
            }
        if (rl == 0) {
            #pragma unroll
            for (int mi = 0; mi < 8; ++mi)
                #pragma unroll
                for (int j = 0; j < 4; ++j)
                    wsum[wn * 256 + wm * 128 + mi * 16 + kg * 4 + j] = rsm[mi][j];
        }
        __syncthreads();
        if (tid < 256) {
            float s = wsum[tid] + wsum[256 + tid] + wsum[512 + tid] + wsum[768 + tid];
            psum[(long)z * szPsum + (long)blockIdx.y * 4096 + blockIdx.x * 256 + tid] = s;
        }
    } else if (EPI == 2) {
        float* C = (float*)C0 + (long)z * szC;
        const float* rs = aux + (long)z * szAux;
        #pragma unroll
        for (int mi = 0; mi < 8; ++mi)
            #pragma unroll
            for (int j = 0; j < 4; ++j) {
                int r = rowg + mi * 16 + j;
                float inv = 1.f / rs[r];
                float* cr = C + (long)r * ldC + colg;
                #pragma unroll
                for (int ni = 0; ni < 4; ++ni) cr[ni * 16] = acc[mi][ni][j] * inv;
            }
    } else {
        float* C = (z < nkz - 1) ? ((float*)C0 + (long)z * szC) : (float*)C1;
        #pragma unroll
        for (int mi = 0; mi < 8; ++mi)
            #pragma unroll
            for (int j = 0; j < 4; ++j) {
                float* cr = C + (long)(rowg + mi * 16 + j) * ldC + colg;
                #pragma unroll
                for (int ni = 0; ni < 4; ++ni) cr[ni * 16] = acc[mi][ni][j];
            }
    }
}

// ---------------------------------------------------------------------------
// bf16 transpose: in [T][D] -> out [D][T], 64x64 tiles via LDS
// ---------------------------------------------------------------------------
__global__ __launch_bounds__(256)
void transpose64(const __bf16* __restrict__ in, __bf16* __restrict__ out,
                 int T, int D, long sIn, long sOut)
{
    __shared__ __bf16 tile[64][72];
    const __bf16* pin  = in  + (long)blockIdx.z * sIn;
    __bf16*       pout = out + (long)blockIdx.z * sOut;
    const int t0 = blockIdx.x * 64, d0 = blockIdx.y * 64;
    const int tid = threadIdx.x;
    const int rr = tid >> 3;
    const int cc = (tid & 7) * 8;

    #pragma unroll
    for (int it = 0; it < 2; ++it) {
        int r = rr + it * 32;
        bf16x8 v = *(const bf16x8*)(pin + (long)(t0 + r) * D + d0 + cc);
        *(bf16x8*)&tile[r][cc] = v;
    }
    __syncthreads();
    #pragma unroll
    for (int it = 0; it < 2; ++it) {
        int dr = rr + it * 32;
        bf16x8 o;
        #pragma unroll
        for (int j = 0; j < 8; ++j) o[j] = tile[cc + j][dr];
        *(bf16x8*)(pout + (long)(d0 + dr) * T + t0 + cc) = o;
    }
}

// rs[b][r] = sum_{cb<16} psum[b][cb][r]
__global__ __launch_bounds__(256)
void rowsum16(const float* __restrict__ psum, float* __restrict__ rs)
{
    int i = blockIdx.x * 256 + threadIdx.x;
    int b = i >> 12, r = i & 4095;
    const float* p = psum + (long)b * 65536 + r;
    float s = 0.f;
    #pragma unroll
    for (int cb = 0; cb < 16; ++cb) s += p[cb * 4096];
    rs[i] = s;
}

// out = (out + sum parts) / rs[row]
__global__ __launch_bounds__(256)
void pv_reduce(float* __restrict__ outb, const float* __restrict__ parts,
               int np, const float* __restrict__ rs)
{
    long i = ((long)blockIdx.x * 256 + threadIdx.x) * 4;
    f32x4 v = *(f32x4*)(outb + i);
    for (int p = 0; p < np; ++p)
        v += *(const f32x4*)(parts + (long)p * 4194304 + i);
    float inv = 1.f / rs[i >> 10];
    v *= inv;
    *(f32x4*)(outb + i) = v;
}

// ---------------------------------------------------------------------------
extern "C" void kernel_launch(void* const* d_in, const int* in_sizes, int n_in,
                              void* d_out, int out_size, void* d_ws, size_t ws_size,
                              hipStream_t stream)
{
    const float* x  = (const float*)d_in[0];
    const float* Wq = (const float*)d_in[1];
    const float* bq = (const float*)d_in[2];
    const float* Wk = (const float*)d_in[3];
    const float* bk = (const float*)d_in[4];
    const float* Wv = (const float*)d_in[5];
    const float* bv = (const float*)d_in[6];
    float* out = (float*)d_out;

    const long T = 4096, E = 1024, D = 1024;
    const long TD = T * D;
    const long TT = T * T;
    const long WB = D * E;
    const float ALPHA = 1.0f / 32.0f;
    char* W = (char*)d_ws;

    const size_t need_A  = 275853312;
    const size_t need_B2 = 191131648;

    if (ws_size >= need_A) {
        __bf16* wall = (__bf16*)(W);
        __bf16* xb   = (__bf16*)(W + 6291456);
        __bf16* vt   = (__bf16*)(W + 39845888);
        __bf16* q    = (__bf16*)(W + 73400320);
        __bf16* k    = (__bf16*)(W + 106954752);
        __bf16* P    = (__bf16*)(W + 140509184);
        float*  psum = (float*) (W + 274726912);
        float*  rs   = (float*) (W + 275775488);
        float*  bp   = (float*) (W + 275841024);

        pack_bias<<<12, 256, 0, stream>>>(bq, bk, bv, bp);
        cvt_f32_bf16<<<512, 256, 0, stream>>>(Wq, wall, WB/8);
        cvt_f32_bf16<<<512, 256, 0, stream>>>(Wk, wall + WB, WB/8);
        cvt_f32_bf16<<<512, 256, 0, stream>>>(Wv, wall + 2*WB, WB/8);
        cvt_f32_bf16<<<4096, 256, 0, stream>>>(x, xb, 4*TD/8);

        gemm8p<0><<<dim3(64,4,3), 512, 0, stream>>>(
            xb, wall, q, nullptr, bp, nullptr,
            1024, 1024, 1024, 16, 0, WB, 4*TD, 1024, 0, 0, 0.f);

        transpose64<<<dim3(64,16,4), 256, 0, stream>>>(P, vt, (int)T, (int)D, TD, TD);

        gemm8p<1><<<dim3(16,16,4), 512, 0, stream>>>(
            q, k, P, nullptr, nullptr, psum,
            1024, 1024, 4096, 16, TD, TD, TT, 0, 65536, 0, ALPHA);

        rowsum16<<<64, 256, 0, stream>>>(psum, rs);

        gemm8p<2><<<dim3(16,4,4), 512, 0, stream>>>(
            P, vt, out, nullptr, rs, nullptr,
            4096, 4096, 1024, 64, TT, TD, TD, 4096, 0, 0, 0.f);
    } else if (ws_size >= need_B2) {
        __bf16* wall  = (__bf16*)(W);
        __bf16* xb    = (__bf16*)(W + 6291456);
        float*  parts = (float*) (W + 6291456);
        __bf16* vt    = (__bf16*)(W + 56623104);
        __bf16* q     = (__bf16*)(W + 90177536);
        __bf16* k     = (__bf16*)(W + 123731968);
        __bf16* P     = (__bf16*)(W + 157286400);
        float*  psum  = (float*) (W + 190840832);
        float*  rs    = (float*) (W + 191102976);
        float*  bp    = (float*) (W + 191119360);

        pack_bias<<<12, 256, 0, stream>>>(bq, bk, bv, bp);
        cvt_f32_bf16<<<512, 256, 0, stream>>>(Wq, wall, WB/8);
        cvt_f32_bf16<<<512, 256, 0, stream>>>(Wk, wall + WB, WB/8);
        cvt_f32_bf16<<<512, 256, 0, stream>>>(Wv, wall + 2*WB, WB/8);
        cvt_f32_bf16<<<4096, 256, 0, stream>>>(x, xb, 4*TD/8);

        gemm8p<0><<<dim3(64,4,3), 512, 0, stream>>>(
            xb, wall, q, nullptr, bp, nullptr,
            1024, 1024, 1024, 16, 0, WB, 4*TD, 1024, 0, 0, 0.f);

        transpose64<<<dim3(64,16,4), 256, 0, stream>>>(P, vt, (int)T, (int)D, TD, TD);

        for (int b = 0; b < 4; ++b) {
            gemm8p<1><<<dim3(16,16,1), 512, 0, stream>>>(
                q + b*TD, k + b*TD, P, nullptr, nullptr, psum,
                1024, 1024, 4096, 16, 0, 0, 0, 0, 0, 0, ALPHA);
            rowsum16<<<16, 256, 0, stream>>>(psum, rs);
            gemm8p<3><<<dim3(16,4,4), 512, 0, stream>>>(
                P, vt + b*TD, parts, out + b*TD, nullptr, nullptr,
                4096, 4096, 1024, 16, 1024, 1024, TD, 0, 0, 4, 0.f);
            pv_reduce<<<4096, 256, 0, stream>>>(out + b*TD, parts, 3, rs);
        }
    } else {
        __bf16* wall  = (__bf16*)(W);
        __bf16* xb    = (__bf16*)(W + 6291456);
        float*  parts = (float*) (W + 6291456);
        __bf16* q     = (__bf16*)(W + 14680064);
        __bf16* k     = (__bf16*)(W + 23068672);
        __bf16* vt    = (__bf16*)(W + 31457280);
        __bf16* P     = (__bf16*)(W + 39845888);
        float*  psum  = (float*) (W + 73400320);
        float*  rs    = (float*) (W + 73662464);
        float*  bp    = (float*) (W + 73678848);

        pack_bias<<<12, 256, 0, stream>>>(bq, bk, bv, bp);
        cvt_f32_bf16<<<512, 256, 0, stream>>>(Wq, wall, WB/8);
        cvt_f32_bf16<<<512, 256, 0, stream>>>(Wk, wall + WB, WB/8);
        cvt_f32_bf16<<<512, 256, 0, stream>>>(Wv, wall + 2*WB, WB/8);

        for (int b = 0; b < 4; ++b) {
            cvt_f32_bf16<<<2048, 256, 0, stream>>>(x + b*TD, xb, TD/8);
            gemm8p<0><<<dim3(16,4,1), 512, 0, stream>>>(
                xb, wall, q, nullptr, bp, nullptr,
                1024, 1024, 1024, 16, 0, 0, 0, 0, 0, 0, 0.f);
            gemm8p<0><<<dim3(16,4,1), 512, 0, stream>>>(
                xb, wall + WB, k, nullptr, bp + 1024, nullptr,
                1024, 1024, 1024, 16, 0, 0, 0, 0, 0, 0, 0.f);
            gemm8p<0><<<dim3(16,4,1), 512, 0, stream>>>(
                xb, wall + 2*WB, P, nullptr, bp + 2048, nullptr,
                1024, 1024, 1024, 16, 0, 0, 0, 0, 0, 0, 0.f);
            transpose64<<<dim3(64,16,1), 256, 0, stream>>>(P, vt, (int)T, (int)D, 0, 0);
            gemm8p<1><<<dim3(16,16,1), 512, 0, stream>>>(
                q, k, P, nullptr, nullptr, psum,
                1024, 1024, 4096, 16, 0, 0, 0, 0, 0, 0, ALPHA);
            rowsum16<<<16, 256, 0, stream>>>(psum, rs);
            gemm8p<3><<<dim3(16,4,2), 512, 0, stream>>>(
                P, vt, parts, out + b*TD, nullptr, nullptr,
                4096, 4096, 1024, 32, 2048, 2048, TD, 0, 0, 2, 0.f);
            pv_reduce<<<4096, 256, 0, stream>>>(out + b*TD, parts, 1, rs);
        }
    }
}